// Round 2
// baseline (860.620 us; speedup 1.0000x reference)
//
#include <hip/hip_runtime.h>
#include <math.h>

#define N_NODES 50000
#define N_EDGES 800000

// workspace layout (float-element offsets)
#define OFF_KN     0
#define OFF_QN     3200000
#define OFF_VN     6400000
#define OFF_AGG    9600000
#define OFF_RS     12800000   // int[50001] CSR row_start
#define OFF_CNT    12860000   // int[50000]
#define OFF_CUR    12920000   // int[50000]
#define OFF_PART   12980000   // int[256]
#define OFF_SMALL  12981000   // int[32]: ncnt[0..3], ncur[4..7], noff[8..12], cbase[16..20]
#define OFF_ORDER  13000000   // int[50000]
#define OFF_COL    13100000   // int[800000]

__device__ __forceinline__ float gelu_f(float a) {
    return 0.5f * a * (1.0f + erff(a * 0.70710678118654752f));
}

__global__ __launch_bounds__(256) void init_k(int* __restrict__ cnt,
                                              int* __restrict__ cur,
                                              int* __restrict__ small) {
    int i = blockIdx.x * 256 + threadIdx.x;
    if (i < N_NODES) { cnt[i] = 0; cur[i] = 0; }
    if (i < 32) small[i] = 0;
}

__global__ __launch_bounds__(256) void hist_k(const int* __restrict__ ei,
                                              const int* __restrict__ ntype,
                                              int* __restrict__ cnt,
                                              int* __restrict__ small) {
    int e = blockIdx.x * 256 + threadIdx.x;      // exact 800000
    atomicAdd(&cnt[ei[N_EDGES + e]], 1);
    if (e < N_NODES) atomicAdd(&small[ntype[e]], 1);
}

__global__ __launch_bounds__(256) void scan1_k(const int* __restrict__ cnt,
                                               int* __restrict__ rs,
                                               int* __restrict__ part) {
    int tid = threadIdx.x;
    int i = blockIdx.x * 256 + tid;
    int lane = tid & 63, w = tid >> 6;
    int c = (i < N_NODES) ? cnt[i] : 0;
    int v = c;
#pragma unroll
    for (int o = 1; o < 64; o <<= 1) { int u = __shfl_up(v, o); if (lane >= o) v += u; }
    __shared__ int wsum[4];
    if (lane == 63) wsum[w] = v;
    __syncthreads();
    int base = 0;
#pragma unroll
    for (int k = 0; k < 4; ++k) if (k < w) base += wsum[k];
    if (i < N_NODES) rs[i] = base + v - c;
    if (tid == 255) part[blockIdx.x] = base + v;
}

__global__ __launch_bounds__(256) void scan2_k(int* __restrict__ part,
                                               int* __restrict__ small) {
    int tid = threadIdx.x;
    int lane = tid & 63, w = tid >> 6;
    int c = (tid < 196) ? part[tid] : 0;
    int v = c;
#pragma unroll
    for (int o = 1; o < 64; o <<= 1) { int u = __shfl_up(v, o); if (lane >= o) v += u; }
    __shared__ int wsum[4];
    if (lane == 63) wsum[w] = v;
    __syncthreads();
    int base = 0;
#pragma unroll
    for (int k = 0; k < 4; ++k) if (k < w) base += wsum[k];
    if (tid < 196) part[tid] = base + v - c;   // exclusive
    if (tid == 0) {
        int o = 0, cb = 0;
#pragma unroll
        for (int t = 0; t < 4; ++t) {
            small[8 + t] = o; small[16 + t] = cb;
            int ct = small[t];
            o += ct; cb += (ct + 63) >> 6;
        }
        small[12] = o; small[20] = cb;
    }
}

__global__ __launch_bounds__(256) void scan3_k(int* __restrict__ rs,
                                               const int* __restrict__ part) {
    int i = blockIdx.x * 256 + threadIdx.x;
    if (i < N_NODES) rs[i] += part[blockIdx.x];
    if (i == 0) rs[N_NODES] = N_EDGES;
}

__global__ __launch_bounds__(256) void scatter_k(const int* __restrict__ ei,
                                                 const int* __restrict__ et,
                                                 const int* __restrict__ ntype,
                                                 const int* __restrict__ rs,
                                                 int* __restrict__ cur,
                                                 int* __restrict__ col,
                                                 int* __restrict__ small,
                                                 int* __restrict__ order) {
    int e = blockIdx.x * 256 + threadIdx.x;      // exact 800000
    int tgt = ei[N_EDGES + e];
    int pos = rs[tgt] + atomicAdd(&cur[tgt], 1);
    col[pos] = ei[e] | (et[e] << 20);
    if (e < N_NODES) {
        int t = ntype[e];
        int p = small[8 + t] + atomicAdd(&small[4 + t], 1);
        order[p] = e;
    }
}

// one 64-node x 16-col slice of a typed linear; weights are wave-uniform (scalar path)
__device__ __forceinline__ void typed_mat16(const float* __restrict__ W,
                                            const float* __restrict__ B,
                                            float* __restrict__ Out,
                                            const float* xs, int lane, int wvu,
                                            int node, bool valid) {
    float acc[16];
    const float* Bp = B + wvu * 16;
#pragma unroll
    for (int c = 0; c < 16; c += 4) {
        float4 b4 = *(const float4*)(Bp + c);
        acc[c] = b4.x; acc[c + 1] = b4.y; acc[c + 2] = b4.z; acc[c + 3] = b4.w;
    }
    const float* Wp = W + wvu * 16;
#pragma unroll 4
    for (int i = 0; i < 64; ++i) {
        float xi = xs[i * 64 + lane];
#pragma unroll
        for (int c = 0; c < 16; c += 4) {
            float4 w4 = *(const float4*)(Wp + i * 64 + c);
            acc[c]     = fmaf(xi, w4.x, acc[c]);
            acc[c + 1] = fmaf(xi, w4.y, acc[c + 1]);
            acc[c + 2] = fmaf(xi, w4.z, acc[c + 2]);
            acc[c + 3] = fmaf(xi, w4.w, acc[c + 3]);
        }
    }
    if (valid) {
        float* Op = Out + node * 64 + wvu * 16;
#pragma unroll
        for (int c = 0; c < 16; c += 4) {
            float4 o4 = { acc[c], acc[c + 1], acc[c + 2], acc[c + 3] };
            *(float4*)(Op + c) = o4;
        }
    }
}

// type-bucketed K/Q/V projections: node-per-lane, wave-uniform weights
__global__ __launch_bounds__(256) void kqv_k(const float* __restrict__ x,
                                             const int* __restrict__ order,
                                             const int* __restrict__ small,
                                             const float* __restrict__ Wk, const float* __restrict__ bk,
                                             const float* __restrict__ Wq, const float* __restrict__ bq,
                                             const float* __restrict__ Wv, const float* __restrict__ bv,
                                             float* __restrict__ Kn, float* __restrict__ Qn,
                                             float* __restrict__ Vn) {
    __shared__ float xs[4096];                   // [i][lane]
    int tid = threadIdx.x, wv = tid >> 6, lane = tid & 63;
    int wid = blockIdx.x;
    int cb1 = small[17], cb2 = small[18], cb3 = small[19], cb4 = small[20];
    if (wid >= cb4) return;
    int t = (wid >= cb1) + (wid >= cb2) + (wid >= cb3);
    int cbt = small[16 + t];
    int noff = small[8 + t], cntt = small[t];
    int pstart = noff + (wid - cbt) * 64;
    int pos = pstart + lane;
    int end = noff + cntt;
    bool valid = pos < end;
    int node = order[valid ? pos : end - 1];
    t = __builtin_amdgcn_readfirstlane(t);
    int wvu = __builtin_amdgcn_readfirstlane(wv);

    const float* xr = x + node * 64 + wvu * 16;
    float4 a0 = *(const float4*)(xr + 0), a1 = *(const float4*)(xr + 4),
           a2 = *(const float4*)(xr + 8), a3 = *(const float4*)(xr + 12);
    float st[16] = { a0.x, a0.y, a0.z, a0.w, a1.x, a1.y, a1.z, a1.w,
                     a2.x, a2.y, a2.z, a2.w, a3.x, a3.y, a3.z, a3.w };
#pragma unroll
    for (int k = 0; k < 16; ++k) xs[(wvu * 16 + k) * 64 + lane] = st[k];
    __syncthreads();

    typed_mat16(Wk + t * 4096, bk + t * 64, Kn, xs, lane, wvu, node, valid);
    typed_mat16(Wq + t * 4096, bq + t * 64, Qn, xs, lane, wvu, node, valid);
    typed_mat16(Wv + t * 4096, bv + t * 64, Vn, xs, lane, wvu, node, valid);
}

// fused per-node edge attention + aggregation (CSR, online softmax, hoisted transforms)
__global__ __launch_bounds__(256) void attn_k(const float* __restrict__ Qn,
                                              const float* __restrict__ Kn,
                                              const float* __restrict__ Vn,
                                              const int* __restrict__ rs,
                                              const int* __restrict__ col,
                                              const float* __restrict__ rel_att,
                                              const float* __restrict__ rel_msg,
                                              const float* __restrict__ rel_pri,
                                              float* __restrict__ agg) {
    __shared__ float lds[2816];
    const int tid = threadIdx.x, wv = tid >> 6, lane = tid & 63;
    const int g = lane >> 4, l = lane & 15;
    const int node = blockIdx.x * 4 + wv;        // exact 12500*4 = 50000
    float* q_s  = lds + wv * 704;                // [64]
    float* qp_s = q_s + 64;                      // [5][64]: qp[r][h*16+d]
    float* o_s  = qp_s + 320;                    // [5][64]

    q_s[lane] = Qn[node * 64 + lane];
    __builtin_amdgcn_wave_barrier();

    const int gb = g * 16;
    float4 qf0 = *(const float4*)(q_s + gb + 0);
    float4 qf1 = *(const float4*)(q_s + gb + 4);
    float4 qf2 = *(const float4*)(q_s + gb + 8);
    float4 qf3 = *(const float4*)(q_s + gb + 12);
    // qp[r][h=g][d=l] = pri[r][g]/4 * sum_f A[r][g][l][f] * q[g][f]
#pragma unroll
    for (int r = 0; r < 5; ++r) {
        const float* A = rel_att + ((r * 4 + g) * 16 + l) * 16;
        float4 a0 = *(const float4*)(A + 0), a1 = *(const float4*)(A + 4),
               a2 = *(const float4*)(A + 8), a3 = *(const float4*)(A + 12);
        float acc = a0.x * qf0.x;
        acc = fmaf(a0.y, qf0.y, acc); acc = fmaf(a0.z, qf0.z, acc); acc = fmaf(a0.w, qf0.w, acc);
        acc = fmaf(a1.x, qf1.x, acc); acc = fmaf(a1.y, qf1.y, acc);
        acc = fmaf(a1.z, qf1.z, acc); acc = fmaf(a1.w, qf1.w, acc);
        acc = fmaf(a2.x, qf2.x, acc); acc = fmaf(a2.y, qf2.y, acc);
        acc = fmaf(a2.z, qf2.z, acc); acc = fmaf(a2.w, qf2.w, acc);
        acc = fmaf(a3.x, qf3.x, acc); acc = fmaf(a3.y, qf3.y, acc);
        acc = fmaf(a3.z, qf3.z, acc); acc = fmaf(a3.w, qf3.w, acc);
        qp_s[r * 64 + gb + l] = acc * rel_pri[r * 4 + g] * 0.25f;
    }
    __builtin_amdgcn_wave_barrier();

    int r0 = rs[node], r1 = rs[node + 1];
    float m0 = -INFINITY, m1 = -INFINITY, m2 = -INFINITY, m3 = -INFINITY;
    float d0 = 0.f, d1 = 0.f, d2 = 0.f, d3 = 0.f;
    float O[20];
#pragma unroll
    for (int k = 0; k < 20; ++k) O[k] = 0.0f;

    int nit = (r1 - r0 + 3) >> 2;
    for (int it = 0; it < nit; ++it) {
        int ce = r0 + it * 4 + g;
        bool act = ce < r1;
        int cc = col[act ? ce : r1 - 1];
        int src = cc & 0xFFFFF;
        int rr = cc >> 20;
        const float* kp = Kn + src * 64 + l;
        float k0 = kp[0], k1 = kp[16], k2 = kp[32], k3 = kp[48];
        const float* vp = Vn + src * 64 + l;
        float v0 = vp[0], v1 = vp[16], v2 = vp[32], v3 = vp[48];
        const float* qq = qp_s + rr * 64 + l;
        float s0 = k0 * qq[0], s1 = k1 * qq[16], s2 = k2 * qq[32], s3 = k3 * qq[48];
#pragma unroll
        for (int mm = 1; mm < 16; mm <<= 1) {
            s0 += __shfl_xor(s0, mm); s1 += __shfl_xor(s1, mm);
            s2 += __shfl_xor(s2, mm); s3 += __shfl_xor(s3, mm);
        }
        if (!act) { s0 = -INFINITY; s1 = -INFINITY; s2 = -INFINITY; s3 = -INFINITY; }
        float t0 = s0, t1 = s1, t2 = s2, t3 = s3;
#pragma unroll
        for (int mm = 16; mm < 64; mm <<= 1) {
            t0 = fmaxf(t0, __shfl_xor(t0, mm)); t1 = fmaxf(t1, __shfl_xor(t1, mm));
            t2 = fmaxf(t2, __shfl_xor(t2, mm)); t3 = fmaxf(t3, __shfl_xor(t3, mm));
        }
        if (t0 > m0 || t1 > m1 || t2 > m2 || t3 > m3) {   // wave-uniform
            float n0 = fmaxf(m0, t0), n1 = fmaxf(m1, t1), n2 = fmaxf(m2, t2), n3 = fmaxf(m3, t3);
            float c0 = __expf(m0 - n0), c1 = __expf(m1 - n1), c2 = __expf(m2 - n2), c3 = __expf(m3 - n3);
            d0 *= c0; d1 *= c1; d2 *= c2; d3 *= c3;
#pragma unroll
            for (int k = 0; k < 5; ++k) {
                O[k * 4 + 0] *= c0; O[k * 4 + 1] *= c1; O[k * 4 + 2] *= c2; O[k * 4 + 3] *= c3;
            }
            m0 = n0; m1 = n1; m2 = n2; m3 = n3;
        }
        float p0 = __expf(s0 - m0), p1 = __expf(s1 - m1), p2 = __expf(s2 - m2), p3 = __expf(s3 - m3);
        float e0 = p0, e1 = p1, e2 = p2, e3 = p3;
#pragma unroll
        for (int mm = 16; mm < 64; mm <<= 1) {
            e0 += __shfl_xor(e0, mm); e1 += __shfl_xor(e1, mm);
            e2 += __shfl_xor(e2, mm); e3 += __shfl_xor(e3, mm);
        }
        d0 += e0; d1 += e1; d2 += e2; d3 += e3;
#pragma unroll
        for (int k = 0; k < 5; ++k) {
            bool mt = (rr == k);
            float w0 = mt ? p0 : 0.0f, w1 = mt ? p1 : 0.0f;
            float w2 = mt ? p2 : 0.0f, w3 = mt ? p3 : 0.0f;
            O[k * 4 + 0] = fmaf(w0, v0, O[k * 4 + 0]);
            O[k * 4 + 1] = fmaf(w1, v1, O[k * 4 + 1]);
            O[k * 4 + 2] = fmaf(w2, v2, O[k * 4 + 2]);
            O[k * 4 + 3] = fmaf(w3, v3, O[k * 4 + 3]);
        }
    }
    // sum slot partials (dims h*16+l are per-lane; 4 slots hold partials)
#pragma unroll
    for (int k = 0; k < 20; ++k) {
        O[k] += __shfl_xor(O[k], 16);
        O[k] += __shfl_xor(O[k], 32);
    }
    if (g == 0) {
#pragma unroll
        for (int k = 0; k < 5; ++k) {
            o_s[k * 64 +  0 + l] = O[k * 4 + 0];
            o_s[k * 64 + 16 + l] = O[k * 4 + 1];
            o_s[k * 64 + 32 + l] = O[k * 4 + 2];
            o_s[k * 64 + 48 + l] = O[k * 4 + 3];
        }
    }
    __builtin_amdgcn_wave_barrier();
    // agg[h=g][f=l] = sum_r sum_d O_r[g][d] * M[r][g][d][l]
    float F = 0.0f;
#pragma unroll
    for (int k = 0; k < 5; ++k) {
        const float* ob = o_s + k * 64 + gb;
        float4 o0 = *(const float4*)(ob + 0), o1 = *(const float4*)(ob + 4),
               o2 = *(const float4*)(ob + 8), o3 = *(const float4*)(ob + 12);
        const float* M = rel_msg + ((k * 4 + g) * 16) * 16 + l;
        F = fmaf(o0.x, M[0],   F); F = fmaf(o0.y, M[16],  F);
        F = fmaf(o0.z, M[32],  F); F = fmaf(o0.w, M[48],  F);
        F = fmaf(o1.x, M[64],  F); F = fmaf(o1.y, M[80],  F);
        F = fmaf(o1.z, M[96],  F); F = fmaf(o1.w, M[112], F);
        F = fmaf(o2.x, M[128], F); F = fmaf(o2.y, M[144], F);
        F = fmaf(o2.z, M[160], F); F = fmaf(o2.w, M[176], F);
        F = fmaf(o3.x, M[192], F); F = fmaf(o3.y, M[208], F);
        F = fmaf(o3.z, M[224], F); F = fmaf(o3.w, M[240], F);
    }
    float dsel = (g & 2) ? ((g & 1) ? d3 : d2) : ((g & 1) ? d1 : d0);
    float rd = (dsel > 0.0f) ? (1.0f / dsel) : 0.0f;
    agg[node * 64 + lane] = F * rd;
}

// gelu -> typed linear -> skip mix -> per-type LayerNorm (bucketed, node-per-lane)
__global__ __launch_bounds__(256) void final_k(const float* __restrict__ x,
                                               const int* __restrict__ order,
                                               const int* __restrict__ small,
                                               const float* __restrict__ agg,
                                               const float* __restrict__ Wa,
                                               const float* __restrict__ ba,
                                               const float* __restrict__ ln_g,
                                               const float* __restrict__ ln_b,
                                               const float* __restrict__ skipw,
                                               float* __restrict__ out) {
    __shared__ float xs[4096];
    __shared__ float res_s[4096];
    int tid = threadIdx.x, wv = tid >> 6, lane = tid & 63;
    int wid = blockIdx.x;
    int cb1 = small[17], cb2 = small[18], cb3 = small[19], cb4 = small[20];
    if (wid >= cb4) return;
    int t = (wid >= cb1) + (wid >= cb2) + (wid >= cb3);
    int cbt = small[16 + t];
    int noff = small[8 + t], cntt = small[t];
    int pstart = noff + (wid - cbt) * 64;
    int pos = pstart + lane;
    int end = noff + cntt;
    bool valid = pos < end;
    int node = order[valid ? pos : end - 1];
    t = __builtin_amdgcn_readfirstlane(t);
    int wvu = __builtin_amdgcn_readfirstlane(wv);

    const float* ar = agg + node * 64 + wvu * 16;
    float4 a0 = *(const float4*)(ar + 0), a1 = *(const float4*)(ar + 4),
           a2 = *(const float4*)(ar + 8), a3 = *(const float4*)(ar + 12);
    float st[16] = { gelu_f(a0.x), gelu_f(a0.y), gelu_f(a0.z), gelu_f(a0.w),
                     gelu_f(a1.x), gelu_f(a1.y), gelu_f(a1.z), gelu_f(a1.w),
                     gelu_f(a2.x), gelu_f(a2.y), gelu_f(a2.z), gelu_f(a2.w),
                     gelu_f(a3.x), gelu_f(a3.y), gelu_f(a3.z), gelu_f(a3.w) };
#pragma unroll
    for (int k = 0; k < 16; ++k) xs[(wvu * 16 + k) * 64 + lane] = st[k];
    __syncthreads();

    float acc[16];
    const float* Bp = ba + t * 64 + wvu * 16;
#pragma unroll
    for (int c = 0; c < 16; c += 4) {
        float4 b4 = *(const float4*)(Bp + c);
        acc[c] = b4.x; acc[c + 1] = b4.y; acc[c + 2] = b4.z; acc[c + 3] = b4.w;
    }
    const float* Wp = Wa + t * 4096 + wvu * 16;
#pragma unroll 4
    for (int i = 0; i < 64; ++i) {
        float xi = xs[i * 64 + lane];
#pragma unroll
        for (int c = 0; c < 16; c += 4) {
            float4 w4 = *(const float4*)(Wp + i * 64 + c);
            acc[c]     = fmaf(xi, w4.x, acc[c]);
            acc[c + 1] = fmaf(xi, w4.y, acc[c + 1]);
            acc[c + 2] = fmaf(xi, w4.z, acc[c + 2]);
            acc[c + 3] = fmaf(xi, w4.w, acc[c + 3]);
        }
    }
    float sk = 1.0f / (1.0f + __expf(-skipw[t]));
    float om = 1.0f - sk;
    const float* xrow = x + node * 64 + wvu * 16;
#pragma unroll
    for (int c = 0; c < 16; c += 4) {
        float4 xv = *(const float4*)(xrow + c);
        acc[c]     = acc[c] * sk + xv.x * om;
        acc[c + 1] = acc[c + 1] * sk + xv.y * om;
        acc[c + 2] = acc[c + 2] * sk + xv.z * om;
        acc[c + 3] = acc[c + 3] * sk + xv.w * om;
    }
#pragma unroll
    for (int k = 0; k < 16; ++k) res_s[(wvu * 16 + k) * 64 + lane] = acc[k];
    __syncthreads();

    float sum = 0.0f, ssq = 0.0f;
#pragma unroll
    for (int c = 0; c < 64; ++c) {
        float rv = res_s[c * 64 + lane];
        sum += rv; ssq = fmaf(rv, rv, ssq);
    }
    float mu = sum * (1.0f / 64.0f);
    float var = ssq * (1.0f / 64.0f) - mu * mu;
    float rstd = rsqrtf(var + 1e-5f);
    const float* lg = ln_g + t * 64 + wvu * 16;
    const float* lb = ln_b + t * 64 + wvu * 16;
    if (valid) {
        float* op = out + node * 64 + wvu * 16;
#pragma unroll
        for (int c = 0; c < 16; c += 4) {
            float4 ov;
            ov.x = (acc[c]     - mu) * rstd * lg[c]     + lb[c];
            ov.y = (acc[c + 1] - mu) * rstd * lg[c + 1] + lb[c + 1];
            ov.z = (acc[c + 2] - mu) * rstd * lg[c + 2] + lb[c + 2];
            ov.w = (acc[c + 3] - mu) * rstd * lg[c + 3] + lb[c + 3];
            *(float4*)(op + c) = ov;
        }
    }
}

extern "C" void kernel_launch(void* const* d_in, const int* in_sizes, int n_in,
                              void* d_out, int out_size, void* d_ws, size_t ws_size,
                              hipStream_t stream) {
    const float* x       = (const float*)d_in[0];
    const int*   ntype   = (const int*)d_in[1];
    const int*   ei      = (const int*)d_in[2];
    const int*   et      = (const int*)d_in[3];
    const float* Wk      = (const float*)d_in[4];
    const float* bk      = (const float*)d_in[5];
    const float* Wq      = (const float*)d_in[6];
    const float* bq      = (const float*)d_in[7];
    const float* Wv      = (const float*)d_in[8];
    const float* bv      = (const float*)d_in[9];
    const float* Wa      = (const float*)d_in[10];
    const float* ba      = (const float*)d_in[11];
    const float* ln_g    = (const float*)d_in[12];
    const float* ln_b    = (const float*)d_in[13];
    const float* rel_pri = (const float*)d_in[14];
    const float* rel_att = (const float*)d_in[15];
    const float* rel_msg = (const float*)d_in[16];
    const float* skipw   = (const float*)d_in[17];
    float* out = (float*)d_out;

    float* ws = (float*)d_ws;
    float* Kn  = ws + OFF_KN;
    float* Qn  = ws + OFF_QN;
    float* Vn  = ws + OFF_VN;
    float* agg = ws + OFF_AGG;
    int* rs    = (int*)(ws + OFF_RS);
    int* cnt   = (int*)(ws + OFF_CNT);
    int* cur   = (int*)(ws + OFF_CUR);
    int* part  = (int*)(ws + OFF_PART);
    int* small = (int*)(ws + OFF_SMALL);
    int* order = (int*)(ws + OFF_ORDER);
    int* col   = (int*)(ws + OFF_COL);

    init_k<<<196, 256, 0, stream>>>(cnt, cur, small);
    hist_k<<<3125, 256, 0, stream>>>(ei, ntype, cnt, small);
    scan1_k<<<196, 256, 0, stream>>>(cnt, rs, part);
    scan2_k<<<1, 256, 0, stream>>>(part, small);
    scan3_k<<<196, 256, 0, stream>>>(rs, part);
    scatter_k<<<3125, 256, 0, stream>>>(ei, et, ntype, rs, cur, col, small, order);
    kqv_k<<<786, 256, 0, stream>>>(x, order, small, Wk, bk, Wq, bq, Wv, bv, Kn, Qn, Vn);
    attn_k<<<12500, 256, 0, stream>>>(Qn, Kn, Vn, rs, col, rel_att, rel_msg, rel_pri, agg);
    final_k<<<786, 256, 0, stream>>>(x, order, small, agg, Wa, ba, ln_g, ln_b, skipw, out);
}

// Round 3
// 295.734 us; speedup vs baseline: 2.9101x; 2.9101x over previous
//
#include <hip/hip_runtime.h>
#include <math.h>

#define N_NODES 50000
#define N_EDGES 800000

// workspace layout (float-element offsets)
#define OFF_KN     0
#define OFF_QN     3200000
#define OFF_VN     6400000
#define OFF_AGG    9600000
#define OFF_RS     12800000   // int[50001] CSR row_start
#define OFF_CNT    12860000   // int[800000]  (stride-16 padded counters)
#define OFF_CUR    13660000   // int[800000]  (stride-16 padded counters)
#define OFF_PART   14460000   // int[256]
#define OFF_SMALL  14460300   // int[32]: cnt[0..3], noff[8..12], cbase[16..20]
#define OFF_BTH    14460400   // int[4*196] per-(type,block) node counts -> scanned bases
#define OFF_ORDER  14461200   // int[50000]
#define OFF_COL    14520000   // int[800000]

__device__ __forceinline__ float gelu_f(float a) {
    return 0.5f * a * (1.0f + erff(a * 0.70710678118654752f));
}

__global__ __launch_bounds__(256) void init_k(int* __restrict__ cnts,
                                              int* __restrict__ small) {
    int i = blockIdx.x * 256 + threadIdx.x;   // exact 6250*256 = 1.6M (cnt+cur)
    cnts[i] = 0;
    if (i < 32) small[i] = 0;
}

// edge histogram into line-padded counters (non-returning atomics only)
__global__ __launch_bounds__(256) void hist_k(const int* __restrict__ ei,
                                              int* __restrict__ cnt) {
    int e = blockIdx.x * 256 + threadIdx.x;      // exact 800000
    atomicAdd(&cnt[ei[N_EDGES + e] << 4], 1);
}

// per-block node-type histogram via ballots (no atomics)
__global__ __launch_bounds__(256) void bhist_k(const int* __restrict__ ntype,
                                               int* __restrict__ bth) {
    __shared__ int wc[4][4];   // [wave][type]
    int tid = threadIdx.x, w = tid >> 6, lane = tid & 63;
    int i = blockIdx.x * 256 + tid;
    int t = (i < N_NODES) ? ntype[i] : 255;
#pragma unroll
    for (int tt = 0; tt < 4; ++tt) {
        unsigned long long m = __ballot(t == tt);
        if (lane == 0) wc[w][tt] = __popcll(m);
    }
    __syncthreads();
    if (tid < 4)
        bth[tid * 196 + blockIdx.x] = wc[0][tid] + wc[1][tid] + wc[2][tid] + wc[3][tid];
}

// scan per-(type,block) counts -> global bases; fill small[] (deterministic, 1 block)
__global__ __launch_bounds__(64) void tscan_k(int* __restrict__ bth,
                                              int* __restrict__ small) {
    __shared__ int tot[4];
    __shared__ int noff_s[4];
    int t = threadIdx.x;
    if (t < 4) {
        int s = 0;
        for (int b = 0; b < 196; ++b) s += bth[t * 196 + b];
        tot[t] = s;
    }
    __syncthreads();
    if (t == 0) {
        int o = 0, cb = 0;
        for (int k = 0; k < 4; ++k) {
            small[k] = tot[k];
            small[8 + k] = o; noff_s[k] = o;
            small[16 + k] = cb;
            o += tot[k]; cb += (tot[k] + 63) >> 6;
        }
        small[12] = o; small[20] = cb;
    }
    __syncthreads();
    if (t < 4) {
        int run = noff_s[t];
        for (int b = 0; b < 196; ++b) {
            int c = bth[t * 196 + b];
            bth[t * 196 + b] = run;
            run += c;
        }
    }
}

// scatter node ids into type-bucketed order[] via ballot ranks (no atomics)
__global__ __launch_bounds__(256) void scatter_order_k(const int* __restrict__ ntype,
                                                       const int* __restrict__ bth,
                                                       int* __restrict__ order) {
    __shared__ int wc[4][4];
    int tid = threadIdx.x, w = tid >> 6, lane = tid & 63;
    int i = blockIdx.x * 256 + tid;
    int t = (i < N_NODES) ? ntype[i] : 255;
    int myrank = 0;
#pragma unroll
    for (int tt = 0; tt < 4; ++tt) {
        unsigned long long m = __ballot(t == tt);
        if (lane == 0) wc[w][tt] = __popcll(m);
        if (t == tt) myrank = __popcll(m & ((1ull << lane) - 1ull));
    }
    __syncthreads();
    if (t < 4) {
        int base = 0;
#pragma unroll
        for (int w2 = 0; w2 < 4; ++w2) if (w2 < w) base += wc[w2][t];
        order[bth[t * 196 + blockIdx.x] + base + myrank] = i;
    }
}

__global__ __launch_bounds__(256) void scan1_k(const int* __restrict__ cnt,
                                               int* __restrict__ rs,
                                               int* __restrict__ part) {
    int tid = threadIdx.x;
    int i = blockIdx.x * 256 + tid;
    int lane = tid & 63, w = tid >> 6;
    int c = (i < N_NODES) ? cnt[i << 4] : 0;
    int v = c;
#pragma unroll
    for (int o = 1; o < 64; o <<= 1) { int u = __shfl_up(v, o); if (lane >= o) v += u; }
    __shared__ int wsum[4];
    if (lane == 63) wsum[w] = v;
    __syncthreads();
    int base = 0;
#pragma unroll
    for (int k = 0; k < 4; ++k) if (k < w) base += wsum[k];
    if (i < N_NODES) rs[i] = base + v - c;
    if (tid == 255) part[blockIdx.x] = base + v;
}

__global__ __launch_bounds__(256) void scan2_k(int* __restrict__ part) {
    int tid = threadIdx.x;
    int lane = tid & 63, w = tid >> 6;
    int c = (tid < 196) ? part[tid] : 0;
    int v = c;
#pragma unroll
    for (int o = 1; o < 64; o <<= 1) { int u = __shfl_up(v, o); if (lane >= o) v += u; }
    __shared__ int wsum[4];
    if (lane == 63) wsum[w] = v;
    __syncthreads();
    int base = 0;
#pragma unroll
    for (int k = 0; k < 4; ++k) if (k < w) base += wsum[k];
    if (tid < 196) part[tid] = base + v - c;   // exclusive
}

__global__ __launch_bounds__(256) void scan3_k(int* __restrict__ rs,
                                               const int* __restrict__ part) {
    int i = blockIdx.x * 256 + threadIdx.x;
    if (i < N_NODES) rs[i] += part[blockIdx.x];
    if (i == 0) rs[N_NODES] = N_EDGES;
}

// CSR column scatter; padded cur counters keep same-line atomic chains at degree depth
__global__ __launch_bounds__(256) void scatter_col_k(const int* __restrict__ ei,
                                                     const int* __restrict__ et,
                                                     const int* __restrict__ rs,
                                                     int* __restrict__ cur,
                                                     int* __restrict__ col) {
    int e = blockIdx.x * 256 + threadIdx.x;      // exact 800000
    int tgt = ei[N_EDGES + e];
    int pos = rs[tgt] + atomicAdd(&cur[tgt << 4], 1);
    col[pos] = ei[e] | (et[e] << 20);
}

// one 64-node x 16-col slice of a typed linear; weights are wave-uniform (scalar path)
__device__ __forceinline__ void typed_mat16(const float* __restrict__ W,
                                            const float* __restrict__ B,
                                            float* __restrict__ Out,
                                            const float* xs, int lane, int wvu,
                                            int node, bool valid) {
    float acc[16];
    const float* Bp = B + wvu * 16;
#pragma unroll
    for (int c = 0; c < 16; c += 4) {
        float4 b4 = *(const float4*)(Bp + c);
        acc[c] = b4.x; acc[c + 1] = b4.y; acc[c + 2] = b4.z; acc[c + 3] = b4.w;
    }
    const float* Wp = W + wvu * 16;
#pragma unroll 4
    for (int i = 0; i < 64; ++i) {
        float xi = xs[i * 64 + lane];
#pragma unroll
        for (int c = 0; c < 16; c += 4) {
            float4 w4 = *(const float4*)(Wp + i * 64 + c);
            acc[c]     = fmaf(xi, w4.x, acc[c]);
            acc[c + 1] = fmaf(xi, w4.y, acc[c + 1]);
            acc[c + 2] = fmaf(xi, w4.z, acc[c + 2]);
            acc[c + 3] = fmaf(xi, w4.w, acc[c + 3]);
        }
    }
    if (valid) {
        float* Op = Out + node * 64 + wvu * 16;
#pragma unroll
        for (int c = 0; c < 16; c += 4) {
            float4 o4 = { acc[c], acc[c + 1], acc[c + 2], acc[c + 3] };
            *(float4*)(Op + c) = o4;
        }
    }
}

// type-bucketed K/Q/V projections: node-per-lane, wave-uniform weights
__global__ __launch_bounds__(256) void kqv_k(const float* __restrict__ x,
                                             const int* __restrict__ order,
                                             const int* __restrict__ small,
                                             const float* __restrict__ Wk, const float* __restrict__ bk,
                                             const float* __restrict__ Wq, const float* __restrict__ bq,
                                             const float* __restrict__ Wv, const float* __restrict__ bv,
                                             float* __restrict__ Kn, float* __restrict__ Qn,
                                             float* __restrict__ Vn) {
    __shared__ float xs[4096];                   // [i][lane]
    int tid = threadIdx.x, wv = tid >> 6, lane = tid & 63;
    int wid = blockIdx.x;
    int cb1 = small[17], cb2 = small[18], cb3 = small[19], cb4 = small[20];
    if (wid >= cb4) return;
    int t = (wid >= cb1) + (wid >= cb2) + (wid >= cb3);
    int cbt = small[16 + t];
    int noff = small[8 + t], cntt = small[t];
    int pstart = noff + (wid - cbt) * 64;
    int pos = pstart + lane;
    int end = noff + cntt;
    bool valid = pos < end;
    int node = order[valid ? pos : end - 1];
    t = __builtin_amdgcn_readfirstlane(t);
    int wvu = __builtin_amdgcn_readfirstlane(wv);

    const float* xr = x + node * 64 + wvu * 16;
    float4 a0 = *(const float4*)(xr + 0), a1 = *(const float4*)(xr + 4),
           a2 = *(const float4*)(xr + 8), a3 = *(const float4*)(xr + 12);
    float st[16] = { a0.x, a0.y, a0.z, a0.w, a1.x, a1.y, a1.z, a1.w,
                     a2.x, a2.y, a2.z, a2.w, a3.x, a3.y, a3.z, a3.w };
#pragma unroll
    for (int k = 0; k < 16; ++k) xs[(wvu * 16 + k) * 64 + lane] = st[k];
    __syncthreads();

    typed_mat16(Wk + t * 4096, bk + t * 64, Kn, xs, lane, wvu, node, valid);
    typed_mat16(Wq + t * 4096, bq + t * 64, Qn, xs, lane, wvu, node, valid);
    typed_mat16(Wv + t * 4096, bv + t * 64, Vn, xs, lane, wvu, node, valid);
}

// fused per-node edge attention + aggregation (CSR, online softmax, hoisted transforms)
__global__ __launch_bounds__(256) void attn_k(const float* __restrict__ Qn,
                                              const float* __restrict__ Kn,
                                              const float* __restrict__ Vn,
                                              const int* __restrict__ rs,
                                              const int* __restrict__ col,
                                              const float* __restrict__ rel_att,
                                              const float* __restrict__ rel_msg,
                                              const float* __restrict__ rel_pri,
                                              float* __restrict__ agg) {
    __shared__ float lds[2816];
    const int tid = threadIdx.x, wv = tid >> 6, lane = tid & 63;
    const int g = lane >> 4, l = lane & 15;
    const int node = blockIdx.x * 4 + wv;        // exact 12500*4 = 50000
    float* q_s  = lds + wv * 704;                // [64]
    float* qp_s = q_s + 64;                      // [5][64]: qp[r][h*16+d]
    float* o_s  = qp_s + 320;                    // [5][64]

    q_s[lane] = Qn[node * 64 + lane];
    __builtin_amdgcn_wave_barrier();

    const int gb = g * 16;
    float4 qf0 = *(const float4*)(q_s + gb + 0);
    float4 qf1 = *(const float4*)(q_s + gb + 4);
    float4 qf2 = *(const float4*)(q_s + gb + 8);
    float4 qf3 = *(const float4*)(q_s + gb + 12);
    // qp[r][h=g][d=l] = pri[r][g]/4 * sum_f A[r][g][l][f] * q[g][f]
#pragma unroll
    for (int r = 0; r < 5; ++r) {
        const float* A = rel_att + ((r * 4 + g) * 16 + l) * 16;
        float4 a0 = *(const float4*)(A + 0), a1 = *(const float4*)(A + 4),
               a2 = *(const float4*)(A + 8), a3 = *(const float4*)(A + 12);
        float acc = a0.x * qf0.x;
        acc = fmaf(a0.y, qf0.y, acc); acc = fmaf(a0.z, qf0.z, acc); acc = fmaf(a0.w, qf0.w, acc);
        acc = fmaf(a1.x, qf1.x, acc); acc = fmaf(a1.y, qf1.y, acc);
        acc = fmaf(a1.z, qf1.z, acc); acc = fmaf(a1.w, qf1.w, acc);
        acc = fmaf(a2.x, qf2.x, acc); acc = fmaf(a2.y, qf2.y, acc);
        acc = fmaf(a2.z, qf2.z, acc); acc = fmaf(a2.w, qf2.w, acc);
        acc = fmaf(a3.x, qf3.x, acc); acc = fmaf(a3.y, qf3.y, acc);
        acc = fmaf(a3.z, qf3.z, acc); acc = fmaf(a3.w, qf3.w, acc);
        qp_s[r * 64 + gb + l] = acc * rel_pri[r * 4 + g] * 0.25f;
    }
    __builtin_amdgcn_wave_barrier();

    int r0 = rs[node], r1 = rs[node + 1];
    float m0 = -INFINITY, m1 = -INFINITY, m2 = -INFINITY, m3 = -INFINITY;
    float d0 = 0.f, d1 = 0.f, d2 = 0.f, d3 = 0.f;
    float O[20];
#pragma unroll
    for (int k = 0; k < 20; ++k) O[k] = 0.0f;

    int nit = (r1 - r0 + 3) >> 2;
    for (int it = 0; it < nit; ++it) {
        int ce = r0 + it * 4 + g;
        bool act = ce < r1;
        int cc = col[act ? ce : r1 - 1];
        int src = cc & 0xFFFFF;
        int rr = cc >> 20;
        const float* kp = Kn + src * 64 + l;
        float k0 = kp[0], k1 = kp[16], k2 = kp[32], k3 = kp[48];
        const float* vp = Vn + src * 64 + l;
        float v0 = vp[0], v1 = vp[16], v2 = vp[32], v3 = vp[48];
        const float* qq = qp_s + rr * 64 + l;
        float s0 = k0 * qq[0], s1 = k1 * qq[16], s2 = k2 * qq[32], s3 = k3 * qq[48];
#pragma unroll
        for (int mm = 1; mm < 16; mm <<= 1) {
            s0 += __shfl_xor(s0, mm); s1 += __shfl_xor(s1, mm);
            s2 += __shfl_xor(s2, mm); s3 += __shfl_xor(s3, mm);
        }
        if (!act) { s0 = -INFINITY; s1 = -INFINITY; s2 = -INFINITY; s3 = -INFINITY; }
        float t0 = s0, t1 = s1, t2 = s2, t3 = s3;
#pragma unroll
        for (int mm = 16; mm < 64; mm <<= 1) {
            t0 = fmaxf(t0, __shfl_xor(t0, mm)); t1 = fmaxf(t1, __shfl_xor(t1, mm));
            t2 = fmaxf(t2, __shfl_xor(t2, mm)); t3 = fmaxf(t3, __shfl_xor(t3, mm));
        }
        if (t0 > m0 || t1 > m1 || t2 > m2 || t3 > m3) {   // wave-uniform
            float n0 = fmaxf(m0, t0), n1 = fmaxf(m1, t1), n2 = fmaxf(m2, t2), n3 = fmaxf(m3, t3);
            float c0 = __expf(m0 - n0), c1 = __expf(m1 - n1), c2 = __expf(m2 - n2), c3 = __expf(m3 - n3);
            d0 *= c0; d1 *= c1; d2 *= c2; d3 *= c3;
#pragma unroll
            for (int k = 0; k < 5; ++k) {
                O[k * 4 + 0] *= c0; O[k * 4 + 1] *= c1; O[k * 4 + 2] *= c2; O[k * 4 + 3] *= c3;
            }
            m0 = n0; m1 = n1; m2 = n2; m3 = n3;
        }
        float p0 = __expf(s0 - m0), p1 = __expf(s1 - m1), p2 = __expf(s2 - m2), p3 = __expf(s3 - m3);
        float e0 = p0, e1 = p1, e2 = p2, e3 = p3;
#pragma unroll
        for (int mm = 16; mm < 64; mm <<= 1) {
            e0 += __shfl_xor(e0, mm); e1 += __shfl_xor(e1, mm);
            e2 += __shfl_xor(e2, mm); e3 += __shfl_xor(e3, mm);
        }
        d0 += e0; d1 += e1; d2 += e2; d3 += e3;
#pragma unroll
        for (int k = 0; k < 5; ++k) {
            bool mt = (rr == k);
            float w0 = mt ? p0 : 0.0f, w1 = mt ? p1 : 0.0f;
            float w2 = mt ? p2 : 0.0f, w3 = mt ? p3 : 0.0f;
            O[k * 4 + 0] = fmaf(w0, v0, O[k * 4 + 0]);
            O[k * 4 + 1] = fmaf(w1, v1, O[k * 4 + 1]);
            O[k * 4 + 2] = fmaf(w2, v2, O[k * 4 + 2]);
            O[k * 4 + 3] = fmaf(w3, v3, O[k * 4 + 3]);
        }
    }
    // sum slot partials (dims h*16+l are per-lane; 4 slots hold partials)
#pragma unroll
    for (int k = 0; k < 20; ++k) {
        O[k] += __shfl_xor(O[k], 16);
        O[k] += __shfl_xor(O[k], 32);
    }
    if (g == 0) {
#pragma unroll
        for (int k = 0; k < 5; ++k) {
            o_s[k * 64 +  0 + l] = O[k * 4 + 0];
            o_s[k * 64 + 16 + l] = O[k * 4 + 1];
            o_s[k * 64 + 32 + l] = O[k * 4 + 2];
            o_s[k * 64 + 48 + l] = O[k * 4 + 3];
        }
    }
    __builtin_amdgcn_wave_barrier();
    // agg[h=g][f=l] = sum_r sum_d O_r[g][d] * M[r][g][d][l]
    float F = 0.0f;
#pragma unroll
    for (int k = 0; k < 5; ++k) {
        const float* ob = o_s + k * 64 + gb;
        float4 o0 = *(const float4*)(ob + 0), o1 = *(const float4*)(ob + 4),
               o2 = *(const float4*)(ob + 8), o3 = *(const float4*)(ob + 12);
        const float* M = rel_msg + ((k * 4 + g) * 16) * 16 + l;
        F = fmaf(o0.x, M[0],   F); F = fmaf(o0.y, M[16],  F);
        F = fmaf(o0.z, M[32],  F); F = fmaf(o0.w, M[48],  F);
        F = fmaf(o1.x, M[64],  F); F = fmaf(o1.y, M[80],  F);
        F = fmaf(o1.z, M[96],  F); F = fmaf(o1.w, M[112], F);
        F = fmaf(o2.x, M[128], F); F = fmaf(o2.y, M[144], F);
        F = fmaf(o2.z, M[160], F); F = fmaf(o2.w, M[176], F);
        F = fmaf(o3.x, M[192], F); F = fmaf(o3.y, M[208], F);
        F = fmaf(o3.z, M[224], F); F = fmaf(o3.w, M[240], F);
    }
    float dsel = (g & 2) ? ((g & 1) ? d3 : d2) : ((g & 1) ? d1 : d0);
    float rd = (dsel > 0.0f) ? (1.0f / dsel) : 0.0f;
    agg[node * 64 + lane] = F * rd;
}

// gelu -> typed linear -> skip mix -> per-type LayerNorm (bucketed, node-per-lane)
__global__ __launch_bounds__(256) void final_k(const float* __restrict__ x,
                                               const int* __restrict__ order,
                                               const int* __restrict__ small,
                                               const float* __restrict__ agg,
                                               const float* __restrict__ Wa,
                                               const float* __restrict__ ba,
                                               const float* __restrict__ ln_g,
                                               const float* __restrict__ ln_b,
                                               const float* __restrict__ skipw,
                                               float* __restrict__ out) {
    __shared__ float xs[4096];
    __shared__ float res_s[4096];
    int tid = threadIdx.x, wv = tid >> 6, lane = tid & 63;
    int wid = blockIdx.x;
    int cb1 = small[17], cb2 = small[18], cb3 = small[19], cb4 = small[20];
    if (wid >= cb4) return;
    int t = (wid >= cb1) + (wid >= cb2) + (wid >= cb3);
    int cbt = small[16 + t];
    int noff = small[8 + t], cntt = small[t];
    int pstart = noff + (wid - cbt) * 64;
    int pos = pstart + lane;
    int end = noff + cntt;
    bool valid = pos < end;
    int node = order[valid ? pos : end - 1];
    t = __builtin_amdgcn_readfirstlane(t);
    int wvu = __builtin_amdgcn_readfirstlane(wv);

    const float* ar = agg + node * 64 + wvu * 16;
    float4 a0 = *(const float4*)(ar + 0), a1 = *(const float4*)(ar + 4),
           a2 = *(const float4*)(ar + 8), a3 = *(const float4*)(ar + 12);
    float st[16] = { gelu_f(a0.x), gelu_f(a0.y), gelu_f(a0.z), gelu_f(a0.w),
                     gelu_f(a1.x), gelu_f(a1.y), gelu_f(a1.z), gelu_f(a1.w),
                     gelu_f(a2.x), gelu_f(a2.y), gelu_f(a2.z), gelu_f(a2.w),
                     gelu_f(a3.x), gelu_f(a3.y), gelu_f(a3.z), gelu_f(a3.w) };
#pragma unroll
    for (int k = 0; k < 16; ++k) xs[(wvu * 16 + k) * 64 + lane] = st[k];
    __syncthreads();

    float acc[16];
    const float* Bp = ba + t * 64 + wvu * 16;
#pragma unroll
    for (int c = 0; c < 16; c += 4) {
        float4 b4 = *(const float4*)(Bp + c);
        acc[c] = b4.x; acc[c + 1] = b4.y; acc[c + 2] = b4.z; acc[c + 3] = b4.w;
    }
    const float* Wp = Wa + t * 4096 + wvu * 16;
#pragma unroll 4
    for (int i = 0; i < 64; ++i) {
        float xi = xs[i * 64 + lane];
#pragma unroll
        for (int c = 0; c < 16; c += 4) {
            float4 w4 = *(const float4*)(Wp + i * 64 + c);
            acc[c]     = fmaf(xi, w4.x, acc[c]);
            acc[c + 1] = fmaf(xi, w4.y, acc[c + 1]);
            acc[c + 2] = fmaf(xi, w4.z, acc[c + 2]);
            acc[c + 3] = fmaf(xi, w4.w, acc[c + 3]);
        }
    }
    float sk = 1.0f / (1.0f + __expf(-skipw[t]));
    float om = 1.0f - sk;
    const float* xrow = x + node * 64 + wvu * 16;
#pragma unroll
    for (int c = 0; c < 16; c += 4) {
        float4 xv = *(const float4*)(xrow + c);
        acc[c]     = acc[c] * sk + xv.x * om;
        acc[c + 1] = acc[c + 1] * sk + xv.y * om;
        acc[c + 2] = acc[c + 2] * sk + xv.z * om;
        acc[c + 3] = acc[c + 3] * sk + xv.w * om;
    }
#pragma unroll
    for (int k = 0; k < 16; ++k) res_s[(wvu * 16 + k) * 64 + lane] = acc[k];
    __syncthreads();

    float sum = 0.0f, ssq = 0.0f;
#pragma unroll
    for (int c = 0; c < 64; ++c) {
        float rv = res_s[c * 64 + lane];
        sum += rv; ssq = fmaf(rv, rv, ssq);
    }
    float mu = sum * (1.0f / 64.0f);
    float var = ssq * (1.0f / 64.0f) - mu * mu;
    float rstd = rsqrtf(var + 1e-5f);
    const float* lg = ln_g + t * 64 + wvu * 16;
    const float* lb = ln_b + t * 64 + wvu * 16;
    if (valid) {
        float* op = out + node * 64 + wvu * 16;
#pragma unroll
        for (int c = 0; c < 16; c += 4) {
            float4 ov;
            ov.x = (acc[c]     - mu) * rstd * lg[c]     + lb[c];
            ov.y = (acc[c + 1] - mu) * rstd * lg[c + 1] + lb[c + 1];
            ov.z = (acc[c + 2] - mu) * rstd * lg[c + 2] + lb[c + 2];
            ov.w = (acc[c + 3] - mu) * rstd * lg[c + 3] + lb[c + 3];
            *(float4*)(op + c) = ov;
        }
    }
}

extern "C" void kernel_launch(void* const* d_in, const int* in_sizes, int n_in,
                              void* d_out, int out_size, void* d_ws, size_t ws_size,
                              hipStream_t stream) {
    const float* x       = (const float*)d_in[0];
    const int*   ntype   = (const int*)d_in[1];
    const int*   ei      = (const int*)d_in[2];
    const int*   et      = (const int*)d_in[3];
    const float* Wk      = (const float*)d_in[4];
    const float* bk      = (const float*)d_in[5];
    const float* Wq      = (const float*)d_in[6];
    const float* bq      = (const float*)d_in[7];
    const float* Wv      = (const float*)d_in[8];
    const float* bv      = (const float*)d_in[9];
    const float* Wa      = (const float*)d_in[10];
    const float* ba      = (const float*)d_in[11];
    const float* ln_g    = (const float*)d_in[12];
    const float* ln_b    = (const float*)d_in[13];
    const float* rel_pri = (const float*)d_in[14];
    const float* rel_att = (const float*)d_in[15];
    const float* rel_msg = (const float*)d_in[16];
    const float* skipw   = (const float*)d_in[17];
    float* out = (float*)d_out;

    float* ws = (float*)d_ws;
    float* Kn  = ws + OFF_KN;
    float* Qn  = ws + OFF_QN;
    float* Vn  = ws + OFF_VN;
    float* agg = ws + OFF_AGG;
    int* rs    = (int*)(ws + OFF_RS);
    int* cnt   = (int*)(ws + OFF_CNT);
    int* cur   = (int*)(ws + OFF_CUR);
    int* part  = (int*)(ws + OFF_PART);
    int* small = (int*)(ws + OFF_SMALL);
    int* bth   = (int*)(ws + OFF_BTH);
    int* order = (int*)(ws + OFF_ORDER);
    int* col   = (int*)(ws + OFF_COL);

    init_k<<<6250, 256, 0, stream>>>(cnt, small);        // zeros cnt+cur (contiguous)
    hist_k<<<3125, 256, 0, stream>>>(ei, cnt);
    bhist_k<<<196, 256, 0, stream>>>(ntype, bth);
    tscan_k<<<1, 64, 0, stream>>>(bth, small);
    scan1_k<<<196, 256, 0, stream>>>(cnt, rs, part);
    scan2_k<<<1, 256, 0, stream>>>(part);
    scan3_k<<<196, 256, 0, stream>>>(rs, part);
    scatter_order_k<<<196, 256, 0, stream>>>(ntype, bth, order);
    scatter_col_k<<<3125, 256, 0, stream>>>(ei, et, rs, cur, col);
    kqv_k<<<786, 256, 0, stream>>>(x, order, small, Wk, bk, Wq, bq, Wv, bv, Kn, Qn, Vn);
    attn_k<<<12500, 256, 0, stream>>>(Qn, Kn, Vn, rs, col, rel_att, rel_msg, rel_pri, agg);
    final_k<<<786, 256, 0, stream>>>(x, order, small, agg, Wa, ba, ln_g, ln_b, skipw, out);
}

// Round 4
// 270.631 us; speedup vs baseline: 3.1800x; 1.0928x over previous
//
#include <hip/hip_runtime.h>
#include <math.h>

#define N_NODES 50000
#define N_EDGES 800000

// workspace layout (float/u32-element offsets)
#define OFF_KV     0          // u32[N*64]: interleaved bf16 (K in lo16, V in hi16)
#define OFF_QN     3200000    // float[N*64]
#define OFF_AGG    6400000    // float[N*64]
#define OFF_RS     9600000    // int[50001] CSR row_start
#define OFF_CNT    9660000    // int[800000]  (stride-16 padded counters)
#define OFF_CUR    10460000   // int[800000]  (stride-16 padded counters)
#define OFF_PART   11260000   // int[256]
#define OFF_SMALL  11260300   // int[32]: cnt[0..3], noff[8..12], cbase[16..20]
#define OFF_BTH    11260400   // int[4*196]
#define OFF_ORDER  11261200   // int[50000]
#define OFF_COL    11320000   // int[800000]

__device__ __forceinline__ float gelu_f(float a) {
    return 0.5f * a * (1.0f + erff(a * 0.70710678118654752f));
}

__device__ __forceinline__ unsigned pack_kv(float kf, float vf) {
    unsigned ku = __float_as_uint(kf);
    ku = (ku + 0x7FFFu + ((ku >> 16) & 1u)) >> 16;
    unsigned vu = __float_as_uint(vf);
    vu = (vu + 0x7FFFu + ((vu >> 16) & 1u)) & 0xFFFF0000u;
    return vu | ku;
}

__global__ __launch_bounds__(256) void init_k(int* __restrict__ cnts,
                                              int* __restrict__ small) {
    int i = blockIdx.x * 256 + threadIdx.x;   // exact 6250*256 = 1.6M (cnt+cur)
    cnts[i] = 0;
    if (i < 32) small[i] = 0;
}

__global__ __launch_bounds__(256) void hist_k(const int* __restrict__ ei,
                                              int* __restrict__ cnt) {
    int e = blockIdx.x * 256 + threadIdx.x;      // exact 800000
    atomicAdd(&cnt[ei[N_EDGES + e] << 4], 1);
}

// per-block node-type histogram via ballots (no atomics)
__global__ __launch_bounds__(256) void bhist_k(const int* __restrict__ ntype,
                                               int* __restrict__ bth) {
    __shared__ int wc[4][4];
    int tid = threadIdx.x, w = tid >> 6, lane = tid & 63;
    int i = blockIdx.x * 256 + tid;
    int t = (i < N_NODES) ? ntype[i] : 255;
#pragma unroll
    for (int tt = 0; tt < 4; ++tt) {
        unsigned long long m = __ballot(t == tt);
        if (lane == 0) wc[w][tt] = __popcll(m);
    }
    __syncthreads();
    if (tid < 4)
        bth[tid * 196 + blockIdx.x] = wc[0][tid] + wc[1][tid] + wc[2][tid] + wc[3][tid];
}

__global__ __launch_bounds__(64) void tscan_k(int* __restrict__ bth,
                                              int* __restrict__ small) {
    __shared__ int tot[4];
    __shared__ int noff_s[4];
    int t = threadIdx.x;
    if (t < 4) {
        int s = 0;
        for (int b = 0; b < 196; ++b) s += bth[t * 196 + b];
        tot[t] = s;
    }
    __syncthreads();
    if (t == 0) {
        int o = 0, cb = 0;
        for (int k = 0; k < 4; ++k) {
            small[k] = tot[k];
            small[8 + k] = o; noff_s[k] = o;
            small[16 + k] = cb;
            o += tot[k]; cb += (tot[k] + 63) >> 6;
        }
        small[12] = o; small[20] = cb;
    }
    __syncthreads();
    if (t < 4) {
        int run = noff_s[t];
        for (int b = 0; b < 196; ++b) {
            int c = bth[t * 196 + b];
            bth[t * 196 + b] = run;
            run += c;
        }
    }
}

__global__ __launch_bounds__(256) void scatter_order_k(const int* __restrict__ ntype,
                                                       const int* __restrict__ bth,
                                                       int* __restrict__ order) {
    __shared__ int wc[4][4];
    int tid = threadIdx.x, w = tid >> 6, lane = tid & 63;
    int i = blockIdx.x * 256 + tid;
    int t = (i < N_NODES) ? ntype[i] : 255;
    int myrank = 0;
#pragma unroll
    for (int tt = 0; tt < 4; ++tt) {
        unsigned long long m = __ballot(t == tt);
        if (lane == 0) wc[w][tt] = __popcll(m);
        if (t == tt) myrank = __popcll(m & ((1ull << lane) - 1ull));
    }
    __syncthreads();
    if (t < 4) {
        int base = 0;
#pragma unroll
        for (int w2 = 0; w2 < 4; ++w2) if (w2 < w) base += wc[w2][t];
        order[bth[t * 196 + blockIdx.x] + base + myrank] = i;
    }
}

__global__ __launch_bounds__(256) void scan1_k(const int* __restrict__ cnt,
                                               int* __restrict__ rs,
                                               int* __restrict__ part) {
    int tid = threadIdx.x;
    int i = blockIdx.x * 256 + tid;
    int lane = tid & 63, w = tid >> 6;
    int c = (i < N_NODES) ? cnt[i << 4] : 0;
    int v = c;
#pragma unroll
    for (int o = 1; o < 64; o <<= 1) { int u = __shfl_up(v, o); if (lane >= o) v += u; }
    __shared__ int wsum[4];
    if (lane == 63) wsum[w] = v;
    __syncthreads();
    int base = 0;
#pragma unroll
    for (int k = 0; k < 4; ++k) if (k < w) base += wsum[k];
    if (i < N_NODES) rs[i] = base + v - c;
    if (tid == 255) part[blockIdx.x] = base + v;
}

__global__ __launch_bounds__(256) void scan2_k(int* __restrict__ part) {
    int tid = threadIdx.x;
    int lane = tid & 63, w = tid >> 6;
    int c = (tid < 196) ? part[tid] : 0;
    int v = c;
#pragma unroll
    for (int o = 1; o < 64; o <<= 1) { int u = __shfl_up(v, o); if (lane >= o) v += u; }
    __shared__ int wsum[4];
    if (lane == 63) wsum[w] = v;
    __syncthreads();
    int base = 0;
#pragma unroll
    for (int k = 0; k < 4; ++k) if (k < w) base += wsum[k];
    if (tid < 196) part[tid] = base + v - c;   // exclusive
}

__global__ __launch_bounds__(256) void scan3_k(int* __restrict__ rs,
                                               const int* __restrict__ part) {
    int i = blockIdx.x * 256 + threadIdx.x;
    if (i < N_NODES) rs[i] += part[blockIdx.x];
    if (i == 0) rs[N_NODES] = N_EDGES;
}

__global__ __launch_bounds__(256) void scatter_col_k(const int* __restrict__ ei,
                                                     const int* __restrict__ et,
                                                     const int* __restrict__ rs,
                                                     int* __restrict__ cur,
                                                     int* __restrict__ col) {
    int e = blockIdx.x * 256 + threadIdx.x;      // exact 800000
    int tgt = ei[N_EDGES + e];
    int pos = rs[tgt] + atomicAdd(&cur[tgt << 4], 1);
    col[pos] = ei[e] | (et[e] << 20);
}

// 64-node x 16-col slice of a typed linear into registers (wave-uniform weights)
__device__ __forceinline__ void mat16(const float* __restrict__ W,
                                      const float* __restrict__ B,
                                      const float* xs, int lane, int wvu,
                                      float acc[16]) {
    const float* Bp = B + wvu * 16;
#pragma unroll
    for (int c = 0; c < 16; c += 4) {
        float4 b4 = *(const float4*)(Bp + c);
        acc[c] = b4.x; acc[c + 1] = b4.y; acc[c + 2] = b4.z; acc[c + 3] = b4.w;
    }
    const float* Wp = W + wvu * 16;
#pragma unroll 4
    for (int i = 0; i < 64; ++i) {
        float xi = xs[i * 64 + lane];
#pragma unroll
        for (int c = 0; c < 16; c += 4) {
            float4 w4 = *(const float4*)(Wp + i * 64 + c);
            acc[c]     = fmaf(xi, w4.x, acc[c]);
            acc[c + 1] = fmaf(xi, w4.y, acc[c + 1]);
            acc[c + 2] = fmaf(xi, w4.z, acc[c + 2]);
            acc[c + 3] = fmaf(xi, w4.w, acc[c + 3]);
        }
    }
}

// type-bucketed projections: Q fp32; K,V packed bf16-interleaved KV dwords
__global__ __launch_bounds__(256) void kqv_k(const float* __restrict__ x,
                                             const int* __restrict__ order,
                                             const int* __restrict__ small,
                                             const float* __restrict__ Wk, const float* __restrict__ bk,
                                             const float* __restrict__ Wq, const float* __restrict__ bq,
                                             const float* __restrict__ Wv, const float* __restrict__ bv,
                                             float* __restrict__ Qn,
                                             unsigned* __restrict__ KVu) {
    __shared__ float xs[4096];
    int tid = threadIdx.x, wv = tid >> 6, lane = tid & 63;
    int wid = blockIdx.x;
    int cb1 = small[17], cb2 = small[18], cb3 = small[19], cb4 = small[20];
    if (wid >= cb4) return;
    int t = (wid >= cb1) + (wid >= cb2) + (wid >= cb3);
    int cbt = small[16 + t];
    int noff = small[8 + t], cntt = small[t];
    int pos = noff + (wid - cbt) * 64 + lane;
    int end = noff + cntt;
    bool valid = pos < end;
    int node = order[valid ? pos : end - 1];
    t = __builtin_amdgcn_readfirstlane(t);
    int wvu = __builtin_amdgcn_readfirstlane(wv);

    const float* xr = x + node * 64 + wvu * 16;
    float4 a0 = *(const float4*)(xr + 0), a1 = *(const float4*)(xr + 4),
           a2 = *(const float4*)(xr + 8), a3 = *(const float4*)(xr + 12);
    float st[16] = { a0.x, a0.y, a0.z, a0.w, a1.x, a1.y, a1.z, a1.w,
                     a2.x, a2.y, a2.z, a2.w, a3.x, a3.y, a3.z, a3.w };
#pragma unroll
    for (int k = 0; k < 16; ++k) xs[(wvu * 16 + k) * 64 + lane] = st[k];
    __syncthreads();

    float aq[16];
    mat16(Wq + t * 4096, bq + t * 64, xs, lane, wvu, aq);
    if (valid) {
        float* Op = Qn + node * 64 + wvu * 16;
#pragma unroll
        for (int c = 0; c < 16; c += 4) {
            float4 o4 = { aq[c], aq[c + 1], aq[c + 2], aq[c + 3] };
            *(float4*)(Op + c) = o4;
        }
    }
    float ak[16], av[16];
    mat16(Wk + t * 4096, bk + t * 64, xs, lane, wvu, ak);
    mat16(Wv + t * 4096, bv + t * 64, xs, lane, wvu, av);
    if (valid) {
        unsigned pk[16];
#pragma unroll
        for (int c = 0; c < 16; ++c) pk[c] = pack_kv(ak[c], av[c]);
        uint4* dst = (uint4*)(KVu + node * 64 + wvu * 16);
#pragma unroll
        for (int c = 0; c < 4; ++c)
            dst[c] = *(uint4*)&pk[c * 4];
    }
}

// fused per-node attention+aggregation: CSR, raw-exp softmax (scores are O(1)-bounded),
// bf16 KV gather (1 dword = K,V pair), register-prefetch pipeline
__global__ __launch_bounds__(256) void attn_k(const float* __restrict__ Qn,
                                              const unsigned* __restrict__ KVu,
                                              const int* __restrict__ rs,
                                              const int* __restrict__ col,
                                              const float* __restrict__ rel_att,
                                              const float* __restrict__ rel_msg,
                                              const float* __restrict__ rel_pri,
                                              float* __restrict__ agg) {
    __shared__ float lds[2816];
    const int tid = threadIdx.x, wv = tid >> 6, lane = tid & 63;
    const int g = lane >> 4, l = lane & 15;
    const int node = blockIdx.x * 4 + wv;        // exact 12500*4 = 50000
    float* q_s  = lds + wv * 704;                // [64]
    float* qp_s = q_s + 64;                      // [5][64]: qp[r][h*16+d]
    float* o_s  = qp_s + 320;                    // [5][64]

    q_s[lane] = Qn[node * 64 + lane];
    __builtin_amdgcn_wave_barrier();

    const int gb = g * 16;
    float4 qf0 = *(const float4*)(q_s + gb + 0);
    float4 qf1 = *(const float4*)(q_s + gb + 4);
    float4 qf2 = *(const float4*)(q_s + gb + 8);
    float4 qf3 = *(const float4*)(q_s + gb + 12);
    // qp[r][h=g][d=l] = pri[r][g]/4 * sum_f A[r][g][l][f] * q[g][f]
#pragma unroll
    for (int r = 0; r < 5; ++r) {
        const float* A = rel_att + ((r * 4 + g) * 16 + l) * 16;
        float4 b0 = *(const float4*)(A + 0), b1 = *(const float4*)(A + 4),
               b2 = *(const float4*)(A + 8), b3 = *(const float4*)(A + 12);
        float acc = b0.x * qf0.x;
        acc = fmaf(b0.y, qf0.y, acc); acc = fmaf(b0.z, qf0.z, acc); acc = fmaf(b0.w, qf0.w, acc);
        acc = fmaf(b1.x, qf1.x, acc); acc = fmaf(b1.y, qf1.y, acc);
        acc = fmaf(b1.z, qf1.z, acc); acc = fmaf(b1.w, qf1.w, acc);
        acc = fmaf(b2.x, qf2.x, acc); acc = fmaf(b2.y, qf2.y, acc);
        acc = fmaf(b2.z, qf2.z, acc); acc = fmaf(b2.w, qf2.w, acc);
        acc = fmaf(b3.x, qf3.x, acc); acc = fmaf(b3.y, qf3.y, acc);
        acc = fmaf(b3.z, qf3.z, acc); acc = fmaf(b3.w, qf3.w, acc);
        qp_s[r * 64 + gb + l] = acc * rel_pri[r * 4 + g] * 0.25f;
    }
    __builtin_amdgcn_wave_barrier();

    int r0 = rs[node], r1 = rs[node + 1];
    int deg = r1 - r0;
    int nit = (deg + 3) >> 2;
    // lane-strided col preload (covers deg<=64; rare deg>64 falls back to global)
    int cidx = r0 + lane;
    int colv = col[(cidx < N_EDGES) ? cidx : (N_EDGES - 1)];

    float dn0 = 0.f, dn1 = 0.f, dn2 = 0.f, dn3 = 0.f;
    float O[20];
#pragma unroll
    for (int k = 0; k < 20; ++k) O[k] = 0.0f;

    int cc_cur = 0;
    unsigned a0 = 0, a1 = 0, a2 = 0, a3 = 0;
    if (nit > 0) {
        cc_cur = __shfl(colv, g);
        const unsigned* kvp = KVu + (unsigned)(cc_cur & 0xFFFFF) * 64 + l;
        a0 = kvp[0]; a1 = kvp[16]; a2 = kvp[32]; a3 = kvp[48];
    }
    for (int t = 0; t < nit; ++t) {
        int cc_nxt = 0;
        unsigned b0 = 0, b1 = 0, b2 = 0, b3 = 0;
        if (t + 1 < nit) {
            int idx = (t + 1) * 4 + g;
            if (t + 1 < 16) {
                cc_nxt = __shfl(colv, idx);
            } else {
                int ci = r0 + idx;
                cc_nxt = col[(ci < N_EDGES) ? ci : (N_EDGES - 1)];
            }
            const unsigned* kvp = KVu + (unsigned)(cc_nxt & 0xFFFFF) * 64 + l;
            b0 = kvp[0]; b1 = kvp[16]; b2 = kvp[32]; b3 = kvp[48];
        }
        int rr = cc_cur >> 20;
        const float* qq = qp_s + rr * 64 + l;
        float k0 = __uint_as_float(a0 << 16), v0 = __uint_as_float(a0 & 0xFFFF0000u);
        float k1 = __uint_as_float(a1 << 16), v1 = __uint_as_float(a1 & 0xFFFF0000u);
        float k2 = __uint_as_float(a2 << 16), v2 = __uint_as_float(a2 & 0xFFFF0000u);
        float k3 = __uint_as_float(a3 << 16), v3 = __uint_as_float(a3 & 0xFFFF0000u);
        float s0 = k0 * qq[0], s1 = k1 * qq[16], s2 = k2 * qq[32], s3 = k3 * qq[48];
#pragma unroll
        for (int mm = 1; mm < 16; mm <<= 1) {
            s0 += __shfl_xor(s0, mm); s1 += __shfl_xor(s1, mm);
            s2 += __shfl_xor(s2, mm); s3 += __shfl_xor(s3, mm);
        }
        bool act = (t * 4 + g) < deg;
        float p0 = act ? __expf(s0) : 0.0f;
        float p1 = act ? __expf(s1) : 0.0f;
        float p2 = act ? __expf(s2) : 0.0f;
        float p3 = act ? __expf(s3) : 0.0f;
        dn0 += p0; dn1 += p1; dn2 += p2; dn3 += p3;
#pragma unroll
        for (int k = 0; k < 5; ++k) {
            bool mt = (rr == k);
            O[k * 4 + 0] = fmaf(mt ? p0 : 0.0f, v0, O[k * 4 + 0]);
            O[k * 4 + 1] = fmaf(mt ? p1 : 0.0f, v1, O[k * 4 + 1]);
            O[k * 4 + 2] = fmaf(mt ? p2 : 0.0f, v2, O[k * 4 + 2]);
            O[k * 4 + 3] = fmaf(mt ? p3 : 0.0f, v3, O[k * 4 + 3]);
        }
        cc_cur = cc_nxt; a0 = b0; a1 = b1; a2 = b2; a3 = b3;
    }
    // one-time cross-group reduces (lanes within a group hold identical den partials)
#pragma unroll
    for (int k = 0; k < 20; ++k) {
        O[k] += __shfl_xor(O[k], 16);
        O[k] += __shfl_xor(O[k], 32);
    }
    dn0 += __shfl_xor(dn0, 16); dn0 += __shfl_xor(dn0, 32);
    dn1 += __shfl_xor(dn1, 16); dn1 += __shfl_xor(dn1, 32);
    dn2 += __shfl_xor(dn2, 16); dn2 += __shfl_xor(dn2, 32);
    dn3 += __shfl_xor(dn3, 16); dn3 += __shfl_xor(dn3, 32);
    if (g == 0) {
#pragma unroll
        for (int k = 0; k < 5; ++k) {
            o_s[k * 64 +  0 + l] = O[k * 4 + 0];
            o_s[k * 64 + 16 + l] = O[k * 4 + 1];
            o_s[k * 64 + 32 + l] = O[k * 4 + 2];
            o_s[k * 64 + 48 + l] = O[k * 4 + 3];
        }
    }
    __builtin_amdgcn_wave_barrier();
    // agg[h=g][f=l] = (sum_r sum_d O_r[g][d] * M[r][g][d][l]) / den[g]
    float F = 0.0f;
#pragma unroll
    for (int k = 0; k < 5; ++k) {
        const float* ob = o_s + k * 64 + gb;
        float4 o0 = *(const float4*)(ob + 0), o1 = *(const float4*)(ob + 4),
               o2 = *(const float4*)(ob + 8), o3 = *(const float4*)(ob + 12);
        const float* M = rel_msg + ((k * 4 + g) * 16) * 16 + l;
        F = fmaf(o0.x, M[0],   F); F = fmaf(o0.y, M[16],  F);
        F = fmaf(o0.z, M[32],  F); F = fmaf(o0.w, M[48],  F);
        F = fmaf(o1.x, M[64],  F); F = fmaf(o1.y, M[80],  F);
        F = fmaf(o1.z, M[96],  F); F = fmaf(o1.w, M[112], F);
        F = fmaf(o2.x, M[128], F); F = fmaf(o2.y, M[144], F);
        F = fmaf(o2.z, M[160], F); F = fmaf(o2.w, M[176], F);
        F = fmaf(o3.x, M[192], F); F = fmaf(o3.y, M[208], F);
        F = fmaf(o3.z, M[224], F); F = fmaf(o3.w, M[240], F);
    }
    float dsel = (g & 2) ? ((g & 1) ? dn3 : dn2) : ((g & 1) ? dn1 : dn0);
    float rd = (dsel > 0.0f) ? (1.0f / dsel) : 0.0f;
    agg[node * 64 + lane] = F * rd;
}

// gelu -> typed linear -> skip mix -> per-type LayerNorm (bucketed, node-per-lane)
__global__ __launch_bounds__(256) void final_k(const float* __restrict__ x,
                                               const int* __restrict__ order,
                                               const int* __restrict__ small,
                                               const float* __restrict__ agg,
                                               const float* __restrict__ Wa,
                                               const float* __restrict__ ba,
                                               const float* __restrict__ ln_g,
                                               const float* __restrict__ ln_b,
                                               const float* __restrict__ skipw,
                                               float* __restrict__ out) {
    __shared__ float xs[4096];
    __shared__ float res_s[4096];
    int tid = threadIdx.x, wv = tid >> 6, lane = tid & 63;
    int wid = blockIdx.x;
    int cb1 = small[17], cb2 = small[18], cb3 = small[19], cb4 = small[20];
    if (wid >= cb4) return;
    int t = (wid >= cb1) + (wid >= cb2) + (wid >= cb3);
    int cbt = small[16 + t];
    int noff = small[8 + t], cntt = small[t];
    int pos = noff + (wid - cbt) * 64 + lane;
    int end = noff + cntt;
    bool valid = pos < end;
    int node = order[valid ? pos : end - 1];
    t = __builtin_amdgcn_readfirstlane(t);
    int wvu = __builtin_amdgcn_readfirstlane(wv);

    const float* ar = agg + node * 64 + wvu * 16;
    float4 a0 = *(const float4*)(ar + 0), a1 = *(const float4*)(ar + 4),
           a2 = *(const float4*)(ar + 8), a3 = *(const float4*)(ar + 12);
    float st[16] = { gelu_f(a0.x), gelu_f(a0.y), gelu_f(a0.z), gelu_f(a0.w),
                     gelu_f(a1.x), gelu_f(a1.y), gelu_f(a1.z), gelu_f(a1.w),
                     gelu_f(a2.x), gelu_f(a2.y), gelu_f(a2.z), gelu_f(a2.w),
                     gelu_f(a3.x), gelu_f(a3.y), gelu_f(a3.z), gelu_f(a3.w) };
#pragma unroll
    for (int k = 0; k < 16; ++k) xs[(wvu * 16 + k) * 64 + lane] = st[k];
    __syncthreads();

    float acc[16];
    const float* Bp = ba + t * 64 + wvu * 16;
#pragma unroll
    for (int c = 0; c < 16; c += 4) {
        float4 b4 = *(const float4*)(Bp + c);
        acc[c] = b4.x; acc[c + 1] = b4.y; acc[c + 2] = b4.z; acc[c + 3] = b4.w;
    }
    const float* Wp = Wa + t * 4096 + wvu * 16;
#pragma unroll 4
    for (int i = 0; i < 64; ++i) {
        float xi = xs[i * 64 + lane];
#pragma unroll
        for (int c = 0; c < 16; c += 4) {
            float4 w4 = *(const float4*)(Wp + i * 64 + c);
            acc[c]     = fmaf(xi, w4.x, acc[c]);
            acc[c + 1] = fmaf(xi, w4.y, acc[c + 1]);
            acc[c + 2] = fmaf(xi, w4.z, acc[c + 2]);
            acc[c + 3] = fmaf(xi, w4.w, acc[c + 3]);
        }
    }
    float sk = 1.0f / (1.0f + __expf(-skipw[t]));
    float om = 1.0f - sk;
    const float* xrow = x + node * 64 + wvu * 16;
#pragma unroll
    for (int c = 0; c < 16; c += 4) {
        float4 xv = *(const float4*)(xrow + c);
        acc[c]     = acc[c] * sk + xv.x * om;
        acc[c + 1] = acc[c + 1] * sk + xv.y * om;
        acc[c + 2] = acc[c + 2] * sk + xv.z * om;
        acc[c + 3] = acc[c + 3] * sk + xv.w * om;
    }
#pragma unroll
    for (int k = 0; k < 16; ++k) res_s[(wvu * 16 + k) * 64 + lane] = acc[k];
    __syncthreads();

    float sum = 0.0f, ssq = 0.0f;
#pragma unroll
    for (int c = 0; c < 64; ++c) {
        float rv = res_s[c * 64 + lane];
        sum += rv; ssq = fmaf(rv, rv, ssq);
    }
    float mu = sum * (1.0f / 64.0f);
    float var = ssq * (1.0f / 64.0f) - mu * mu;
    float rstd = rsqrtf(var + 1e-5f);
    const float* lg = ln_g + t * 64 + wvu * 16;
    const float* lb = ln_b + t * 64 + wvu * 16;
    if (valid) {
        float* op = out + node * 64 + wvu * 16;
#pragma unroll
        for (int c = 0; c < 16; c += 4) {
            float4 ov;
            ov.x = (acc[c]     - mu) * rstd * lg[c]     + lb[c];
            ov.y = (acc[c + 1] - mu) * rstd * lg[c + 1] + lb[c + 1];
            ov.z = (acc[c + 2] - mu) * rstd * lg[c + 2] + lb[c + 2];
            ov.w = (acc[c + 3] - mu) * rstd * lg[c + 3] + lb[c + 3];
            *(float4*)(op + c) = ov;
        }
    }
}

extern "C" void kernel_launch(void* const* d_in, const int* in_sizes, int n_in,
                              void* d_out, int out_size, void* d_ws, size_t ws_size,
                              hipStream_t stream) {
    const float* x       = (const float*)d_in[0];
    const int*   ntype   = (const int*)d_in[1];
    const int*   ei      = (const int*)d_in[2];
    const int*   et      = (const int*)d_in[3];
    const float* Wk      = (const float*)d_in[4];
    const float* bk      = (const float*)d_in[5];
    const float* Wq      = (const float*)d_in[6];
    const float* bq      = (const float*)d_in[7];
    const float* Wv      = (const float*)d_in[8];
    const float* bv      = (const float*)d_in[9];
    const float* Wa      = (const float*)d_in[10];
    const float* ba      = (const float*)d_in[11];
    const float* ln_g    = (const float*)d_in[12];
    const float* ln_b    = (const float*)d_in[13];
    const float* rel_pri = (const float*)d_in[14];
    const float* rel_att = (const float*)d_in[15];
    const float* rel_msg = (const float*)d_in[16];
    const float* skipw   = (const float*)d_in[17];
    float* out = (float*)d_out;

    float* ws = (float*)d_ws;
    unsigned* KVu = (unsigned*)(ws + OFF_KV);
    float* Qn  = ws + OFF_QN;
    float* agg = ws + OFF_AGG;
    int* rs    = (int*)(ws + OFF_RS);
    int* cnt   = (int*)(ws + OFF_CNT);
    int* cur   = (int*)(ws + OFF_CUR);
    int* part  = (int*)(ws + OFF_PART);
    int* small = (int*)(ws + OFF_SMALL);
    int* bth   = (int*)(ws + OFF_BTH);
    int* order = (int*)(ws + OFF_ORDER);
    int* col   = (int*)(ws + OFF_COL);

    init_k<<<6250, 256, 0, stream>>>(cnt, small);
    hist_k<<<3125, 256, 0, stream>>>(ei, cnt);
    bhist_k<<<196, 256, 0, stream>>>(ntype, bth);
    tscan_k<<<1, 64, 0, stream>>>(bth, small);
    scan1_k<<<196, 256, 0, stream>>>(cnt, rs, part);
    scan2_k<<<1, 256, 0, stream>>>(part);
    scan3_k<<<196, 256, 0, stream>>>(rs, part);
    scatter_order_k<<<196, 256, 0, stream>>>(ntype, bth, order);
    scatter_col_k<<<3125, 256, 0, stream>>>(ei, et, rs, cur, col);
    kqv_k<<<786, 256, 0, stream>>>(x, order, small, Wk, bk, Wq, bq, Wv, bv, Qn, KVu);
    attn_k<<<12500, 256, 0, stream>>>(Qn, KVu, rs, col, rel_att, rel_msg, rel_pri, agg);
    final_k<<<786, 256, 0, stream>>>(x, order, small, agg, Wa, ba, ln_g, ln_b, skipw, out);
}

// Round 5
// 262.354 us; speedup vs baseline: 3.2804x; 1.0315x over previous
//
#include <hip/hip_runtime.h>
#include <math.h>

#define N_NODES 50000
#define N_EDGES 800000

// workspace layout (float/u32-element offsets)
#define OFF_KV     0          // u32[N*64]: interleaved bf16 (K lo16, V hi16)
#define OFF_QN     3200000    // float[N*64]
#define OFF_AGG    6400000    // float[N*64]
#define OFF_RS     9600000    // int[50001]
#define OFF_CNT    9660000    // int[800000] (stride-16 padded degree counters)
#define OFF_PART   10460000   // int[256]
#define OFF_SMALL  10460300   // int[32]
#define OFF_BTH    10460400   // int[4*196]
#define OFF_ORDER  10461200   // int[50000]
#define OFF_COL    10520000   // int[800000]

__device__ __forceinline__ float gelu_f(float a) {
    return 0.5f * a * (1.0f + erff(a * 0.70710678118654752f));
}

__device__ __forceinline__ unsigned pack_kv(float kf, float vf) {
    unsigned ku = __float_as_uint(kf);
    ku = (ku + 0x7FFFu + ((ku >> 16) & 1u)) >> 16;
    unsigned vu = __float_as_uint(vf);
    vu = (vu + 0x7FFFu + ((vu >> 16) & 1u)) & 0xFFFF0000u;
    return vu | ku;
}

// edge-degree histogram (padded counters) + fused per-block node-type histogram
__global__ __launch_bounds__(256) void hist_k(const int* __restrict__ ei,
                                              const int* __restrict__ ntype,
                                              int* __restrict__ cnt,
                                              int* __restrict__ bth) {
    int e = blockIdx.x * 256 + threadIdx.x;      // exact 800000
    atomicAdd(&cnt[ei[N_EDGES + e] << 4], 1);
    if (blockIdx.x < 196) {
        __shared__ int wc[4][4];
        int tid = threadIdx.x, w = tid >> 6, lane = tid & 63;
        int i = blockIdx.x * 256 + tid;
        int t = (i < N_NODES) ? ntype[i] : 255;
#pragma unroll
        for (int tt = 0; tt < 4; ++tt) {
            unsigned long long m = __ballot(t == tt);
            if (lane == 0) wc[w][tt] = __popcll(m);
        }
        __syncthreads();
        if (tid < 4)
            bth[tid * 196 + blockIdx.x] = wc[0][tid] + wc[1][tid] + wc[2][tid] + wc[3][tid];
    }
}

__global__ __launch_bounds__(64) void tscan_k(int* __restrict__ bth,
                                              int* __restrict__ small) {
    __shared__ int tot[4];
    __shared__ int noff_s[4];
    int t = threadIdx.x;
    if (t < 4) {
        int s = 0;
        for (int b = 0; b < 196; ++b) s += bth[t * 196 + b];
        tot[t] = s;
    }
    __syncthreads();
    if (t == 0) {
        int o = 0, cb = 0;
        for (int k = 0; k < 4; ++k) {
            small[k] = tot[k];
            small[8 + k] = o; noff_s[k] = o;
            small[16 + k] = cb;
            o += tot[k]; cb += (tot[k] + 63) >> 6;
        }
        small[12] = o; small[20] = cb;
    }
    __syncthreads();
    if (t < 4) {
        int run = noff_s[t];
        for (int b = 0; b < 196; ++b) {
            int c = bth[t * 196 + b];
            bth[t * 196 + b] = run;
            run += c;
        }
    }
}

__global__ __launch_bounds__(256) void scan1_k(const int* __restrict__ cnt,
                                               int* __restrict__ rs,
                                               int* __restrict__ part) {
    int tid = threadIdx.x;
    int i = blockIdx.x * 256 + tid;
    int lane = tid & 63, w = tid >> 6;
    int c = (i < N_NODES) ? cnt[i << 4] : 0;
    int v = c;
#pragma unroll
    for (int o = 1; o < 64; o <<= 1) { int u = __shfl_up(v, o); if (lane >= o) v += u; }
    __shared__ int wsum[4];
    if (lane == 63) wsum[w] = v;
    __syncthreads();
    int base = 0;
#pragma unroll
    for (int k = 0; k < 4; ++k) if (k < w) base += wsum[k];
    if (i < N_NODES) rs[i] = base + v - c;
    if (tid == 255) part[blockIdx.x] = base + v;
}

__global__ __launch_bounds__(256) void scan2_k(int* __restrict__ part) {
    int tid = threadIdx.x;
    int lane = tid & 63, w = tid >> 6;
    int c = (tid < 196) ? part[tid] : 0;
    int v = c;
#pragma unroll
    for (int o = 1; o < 64; o <<= 1) { int u = __shfl_up(v, o); if (lane >= o) v += u; }
    __shared__ int wsum[4];
    if (lane == 63) wsum[w] = v;
    __syncthreads();
    int base = 0;
#pragma unroll
    for (int k = 0; k < 4; ++k) if (k < w) base += wsum[k];
    if (tid < 196) part[tid] = base + v - c;   // exclusive
}

// finalize rs + fused type-bucket scatter (ballot ranks, no atomics)
__global__ __launch_bounds__(256) void scan3_k(int* __restrict__ rs,
                                               const int* __restrict__ part,
                                               const int* __restrict__ ntype,
                                               const int* __restrict__ bth,
                                               int* __restrict__ order) {
    int tid = threadIdx.x, w = tid >> 6, lane = tid & 63;
    int i = blockIdx.x * 256 + tid;
    if (i < N_NODES) rs[i] += part[blockIdx.x];
    if (i == 0) rs[N_NODES] = N_EDGES;
    __shared__ int wc[4][4];
    int t = (i < N_NODES) ? ntype[i] : 255;
    int myrank = 0;
#pragma unroll
    for (int tt = 0; tt < 4; ++tt) {
        unsigned long long m = __ballot(t == tt);
        if (lane == 0) wc[w][tt] = __popcll(m);
        if (t == tt) myrank = __popcll(m & ((1ull << lane) - 1ull));
    }
    __syncthreads();
    if (t < 4) {
        int base = 0;
#pragma unroll
        for (int w2 = 0; w2 < 4; ++w2) if (w2 < w) base += wc[w2][t];
        order[bth[t * 196 + blockIdx.x] + base + myrank] = i;
    }
}

// CSR column scatter; consumes cnt by atomic decrement (in-row order reversed, harmless)
__global__ __launch_bounds__(256) void scatter_col_k(const int* __restrict__ ei,
                                                     const int* __restrict__ et,
                                                     const int* __restrict__ rs,
                                                     int* __restrict__ cnt,
                                                     int* __restrict__ col) {
    int e = blockIdx.x * 256 + threadIdx.x;      // exact 800000
    int tgt = ei[N_EDGES + e];
    int old = atomicSub(&cnt[tgt << 4], 1);
    col[rs[tgt] + old - 1] = ei[e] | (et[e] << 20);
}

// 64-node x 16-col slice of a typed linear into registers (wave-uniform weights)
__device__ __forceinline__ void mat16(const float* __restrict__ W,
                                      const float* __restrict__ B,
                                      const float* xs, int lane, int wvu,
                                      float acc[16]) {
    const float* Bp = B + wvu * 16;
#pragma unroll
    for (int c = 0; c < 16; c += 4) {
        float4 b4 = *(const float4*)(Bp + c);
        acc[c] = b4.x; acc[c + 1] = b4.y; acc[c + 2] = b4.z; acc[c + 3] = b4.w;
    }
    const float* Wp = W + wvu * 16;
#pragma unroll 4
    for (int i = 0; i < 64; ++i) {
        float xi = xs[i * 64 + lane];
#pragma unroll
        for (int c = 0; c < 16; c += 4) {
            float4 w4 = *(const float4*)(Wp + i * 64 + c);
            acc[c]     = fmaf(xi, w4.x, acc[c]);
            acc[c + 1] = fmaf(xi, w4.y, acc[c + 1]);
            acc[c + 2] = fmaf(xi, w4.z, acc[c + 2]);
            acc[c + 3] = fmaf(xi, w4.w, acc[c + 3]);
        }
    }
}

__global__ __launch_bounds__(256) void kqv_k(const float* __restrict__ x,
                                             const int* __restrict__ order,
                                             const int* __restrict__ small,
                                             const float* __restrict__ Wk, const float* __restrict__ bk,
                                             const float* __restrict__ Wq, const float* __restrict__ bq,
                                             const float* __restrict__ Wv, const float* __restrict__ bv,
                                             float* __restrict__ Qn,
                                             unsigned* __restrict__ KVu) {
    __shared__ float xs[4096];
    int tid = threadIdx.x, wv = tid >> 6, lane = tid & 63;
    int wid = blockIdx.x;
    int cb1 = small[17], cb2 = small[18], cb3 = small[19], cb4 = small[20];
    if (wid >= cb4) return;
    int t = (wid >= cb1) + (wid >= cb2) + (wid >= cb3);
    int cbt = small[16 + t];
    int noff = small[8 + t], cntt = small[t];
    int pos = noff + (wid - cbt) * 64 + lane;
    int end = noff + cntt;
    bool valid = pos < end;
    int node = order[valid ? pos : end - 1];
    t = __builtin_amdgcn_readfirstlane(t);
    int wvu = __builtin_amdgcn_readfirstlane(wv);

    const float* xr = x + node * 64 + wvu * 16;
    float4 a0 = *(const float4*)(xr + 0), a1 = *(const float4*)(xr + 4),
           a2 = *(const float4*)(xr + 8), a3 = *(const float4*)(xr + 12);
    float st[16] = { a0.x, a0.y, a0.z, a0.w, a1.x, a1.y, a1.z, a1.w,
                     a2.x, a2.y, a2.z, a2.w, a3.x, a3.y, a3.z, a3.w };
#pragma unroll
    for (int k = 0; k < 16; ++k) xs[(wvu * 16 + k) * 64 + lane] = st[k];
    __syncthreads();

    float aq[16];
    mat16(Wq + t * 4096, bq + t * 64, xs, lane, wvu, aq);
    if (valid) {
        float* Op = Qn + node * 64 + wvu * 16;
#pragma unroll
        for (int c = 0; c < 16; c += 4) {
            float4 o4 = { aq[c], aq[c + 1], aq[c + 2], aq[c + 3] };
            *(float4*)(Op + c) = o4;
        }
    }
    float ak[16], av[16];
    mat16(Wk + t * 4096, bk + t * 64, xs, lane, wvu, ak);
    mat16(Wv + t * 4096, bv + t * 64, xs, lane, wvu, av);
    if (valid) {
        unsigned pk[16];
#pragma unroll
        for (int c = 0; c < 16; ++c) pk[c] = pack_kv(ak[c], av[c]);
        uint4* dst = (uint4*)(KVu + node * 64 + wvu * 16);
#pragma unroll
        for (int c = 0; c < 4; ++c)
            dst[c] = *(uint4*)&pk[c * 4];
    }
}

#define BF_LO(u) __uint_as_float((u) << 16)
#define BF_HI(u) __uint_as_float((u) & 0xFFFF0000u)

// load tile T into buffer (CC, AA, BB); safe-clamped indices
#define LOADB(CC, AA, BB, T) do {                                          \
    int idx_ = (T) * 4 + g; if (idx_ > deg - 1) idx_ = deg - 1;            \
    int cc_;                                                               \
    if ((T) < 16) cc_ = __shfl(colv, idx_);                                \
    else          cc_ = col[r0 + idx_];                                    \
    (CC) = cc_;                                                            \
    const unsigned* kvp_ = KVu + (unsigned)(cc_ & 0xFFFFF) * 64;           \
    (AA) = *(const uint2*)(kvp_ + 2 * l);                                  \
    (BB) = *(const uint2*)(kvp_ + 32 + 2 * l);                             \
} while (0)

#define COMPUTE(CC, AA, BB, T) do {                                        \
    int rr_ = (CC) >> 20;                                                  \
    const float* qq_ = qp_s + rr_ * 64 + 2 * l;                            \
    float2 qA_ = *(const float2*)qq_;                                      \
    float2 qB_ = *(const float2*)(qq_ + 32);                               \
    float kA0_ = BF_LO((AA).x), vA0_ = BF_HI((AA).x);                      \
    float kA1_ = BF_LO((AA).y), vA1_ = BF_HI((AA).y);                      \
    float kB0_ = BF_LO((BB).x), vB0_ = BF_HI((BB).x);                      \
    float kB1_ = BF_LO((BB).y), vB1_ = BF_HI((BB).y);                      \
    float sA_ = fmaf(kA1_, qA_.y, kA0_ * qA_.x);                           \
    float sB_ = fmaf(kB1_, qB_.y, kB0_ * qB_.x);                           \
    sA_ += __shfl_xor(sA_, 1); sB_ += __shfl_xor(sB_, 1);                  \
    sA_ += __shfl_xor(sA_, 2); sB_ += __shfl_xor(sB_, 2);                  \
    sA_ += __shfl_xor(sA_, 4); sB_ += __shfl_xor(sB_, 4);                  \
    bool act_ = ((T) * 4 + g) < deg;                                       \
    float pA_ = act_ ? __expf(sA_) : 0.0f;                                 \
    float pB_ = act_ ? __expf(sB_) : 0.0f;                                 \
    dnA += pA_; dnB += pB_;                                                \
    _Pragma("unroll")                                                      \
    for (int k_ = 0; k_ < 5; ++k_) {                                       \
        bool mk_ = (rr_ == k_);                                            \
        float pAk_ = mk_ ? pA_ : 0.0f, pBk_ = mk_ ? pB_ : 0.0f;            \
        OA[k_].x = fmaf(pAk_, vA0_, OA[k_].x);                             \
        OA[k_].y = fmaf(pAk_, vA1_, OA[k_].y);                             \
        OB[k_].x = fmaf(pBk_, vB0_, OB[k_].x);                             \
        OB[k_].y = fmaf(pBk_, vB1_, OB[k_].y);                             \
    }                                                                      \
} while (0)

// fused per-node attention+aggregation: pairwise lane layout, dwordx2 gathers,
// depth-3 register prefetch, raw-exp softmax (scores O(1)-bounded)
__global__ __launch_bounds__(256) void attn_k(const float* __restrict__ Qn,
                                              const unsigned* __restrict__ KVu,
                                              const int* __restrict__ rs,
                                              const int* __restrict__ col,
                                              const float* __restrict__ rel_att,
                                              const float* __restrict__ rel_msg,
                                              const float* __restrict__ rel_pri,
                                              float* __restrict__ agg) {
    __shared__ float lds[2816];
    const int tid = threadIdx.x, wv = tid >> 6, lane = tid & 63;
    const int g = lane >> 4, l = lane & 15;
    const int node = blockIdx.x * 4 + wv;        // exact 12500*4 = 50000
    float* q_s  = lds + wv * 704;                // [64] (reused for den[4] later)
    float* qp_s = q_s + 64;                      // [5][64]: qp[r][h*16+d]
    float* o_s  = qp_s + 320;                    // [5][64]

    q_s[lane] = Qn[node * 64 + lane];
    __builtin_amdgcn_wave_barrier();

    const int gb = g * 16;
    float4 qf0 = *(const float4*)(q_s + gb + 0);
    float4 qf1 = *(const float4*)(q_s + gb + 4);
    float4 qf2 = *(const float4*)(q_s + gb + 8);
    float4 qf3 = *(const float4*)(q_s + gb + 12);
#pragma unroll
    for (int r = 0; r < 5; ++r) {
        const float* A = rel_att + ((r * 4 + g) * 16 + l) * 16;
        float4 b0 = *(const float4*)(A + 0), b1 = *(const float4*)(A + 4),
               b2 = *(const float4*)(A + 8), b3 = *(const float4*)(A + 12);
        float acc = b0.x * qf0.x;
        acc = fmaf(b0.y, qf0.y, acc); acc = fmaf(b0.z, qf0.z, acc); acc = fmaf(b0.w, qf0.w, acc);
        acc = fmaf(b1.x, qf1.x, acc); acc = fmaf(b1.y, qf1.y, acc);
        acc = fmaf(b1.z, qf1.z, acc); acc = fmaf(b1.w, qf1.w, acc);
        acc = fmaf(b2.x, qf2.x, acc); acc = fmaf(b2.y, qf2.y, acc);
        acc = fmaf(b2.z, qf2.z, acc); acc = fmaf(b2.w, qf2.w, acc);
        acc = fmaf(b3.x, qf3.x, acc); acc = fmaf(b3.y, qf3.y, acc);
        acc = fmaf(b3.z, qf3.z, acc); acc = fmaf(b3.w, qf3.w, acc);
        qp_s[r * 64 + gb + l] = acc * rel_pri[r * 4 + g] * 0.25f;
    }
    __builtin_amdgcn_wave_barrier();

    int r0 = rs[node], r1 = rs[node + 1];
    int deg = r1 - r0;
    if (deg == 0) {
        agg[node * 64 + lane] = 0.0f;
        return;
    }
    int nit = (deg + 3) >> 2;
    int cidx = r0 + lane;
    int colv = col[(cidx < N_EDGES) ? cidx : (N_EDGES - 1)];

    float dnA = 0.0f, dnB = 0.0f;
    float2 OA[5], OB[5];
#pragma unroll
    for (int k = 0; k < 5; ++k) { OA[k] = {0.f, 0.f}; OB[k] = {0.f, 0.f}; }

    int c0, c1, c2;
    uint2 A0, B0, A1, B1, A2, B2;
    LOADB(c0, A0, B0, 0);
    LOADB(c1, A1, B1, 1);
    LOADB(c2, A2, B2, 2);

    int t = 0;
    for (;;) {
        COMPUTE(c0, A0, B0, t); if (t + 3 < nit) LOADB(c0, A0, B0, t + 3);
        if (++t >= nit) break;
        COMPUTE(c1, A1, B1, t); if (t + 3 < nit) LOADB(c1, A1, B1, t + 3);
        if (++t >= nit) break;
        COMPUTE(c2, A2, B2, t); if (t + 3 < nit) LOADB(c2, A2, B2, t + 3);
        if (++t >= nit) break;
    }

    // cross-group (edge-slot) reduction
#pragma unroll
    for (int k = 0; k < 5; ++k) {
        OA[k].x += __shfl_xor(OA[k].x, 16); OA[k].x += __shfl_xor(OA[k].x, 32);
        OA[k].y += __shfl_xor(OA[k].y, 16); OA[k].y += __shfl_xor(OA[k].y, 32);
        OB[k].x += __shfl_xor(OB[k].x, 16); OB[k].x += __shfl_xor(OB[k].x, 32);
        OB[k].y += __shfl_xor(OB[k].y, 16); OB[k].y += __shfl_xor(OB[k].y, 32);
    }
    dnA += __shfl_xor(dnA, 16); dnA += __shfl_xor(dnA, 32);
    dnB += __shfl_xor(dnB, 16); dnB += __shfl_xor(dnB, 32);

    if (g == 0) {
#pragma unroll
        for (int k = 0; k < 5; ++k) {
            *(float2*)(o_s + k * 64 + 2 * l) = OA[k];
            *(float2*)(o_s + k * 64 + 32 + 2 * l) = OB[k];
        }
        if (l == 0) { q_s[0] = dnA; q_s[2] = dnB; }   // den0, den2
        if (l == 8) { q_s[1] = dnA; q_s[3] = dnB; }   // den1, den3
    }
    __builtin_amdgcn_wave_barrier();

    // agg[h=g][f=l] = (sum_r sum_d O_r[g][d] * M[r][g][d][l]) / den[g]
    float F = 0.0f;
#pragma unroll
    for (int k = 0; k < 5; ++k) {
        const float* ob = o_s + k * 64 + gb;
        float4 o0 = *(const float4*)(ob + 0), o1 = *(const float4*)(ob + 4),
               o2 = *(const float4*)(ob + 8), o3 = *(const float4*)(ob + 12);
        const float* M = rel_msg + ((k * 4 + g) * 16) * 16 + l;
        F = fmaf(o0.x, M[0],   F); F = fmaf(o0.y, M[16],  F);
        F = fmaf(o0.z, M[32],  F); F = fmaf(o0.w, M[48],  F);
        F = fmaf(o1.x, M[64],  F); F = fmaf(o1.y, M[80],  F);
        F = fmaf(o1.z, M[96],  F); F = fmaf(o1.w, M[112], F);
        F = fmaf(o2.x, M[128], F); F = fmaf(o2.y, M[144], F);
        F = fmaf(o2.z, M[160], F); F = fmaf(o2.w, M[176], F);
        F = fmaf(o3.x, M[192], F); F = fmaf(o3.y, M[208], F);
        F = fmaf(o3.z, M[224], F); F = fmaf(o3.w, M[240], F);
    }
    float dsel = q_s[g];
    float rd = (dsel > 0.0f) ? (1.0f / dsel) : 0.0f;
    agg[node * 64 + lane] = F * rd;
}

// gelu -> typed linear -> skip mix -> per-type LayerNorm (bucketed, node-per-lane)
__global__ __launch_bounds__(256) void final_k(const float* __restrict__ x,
                                               const int* __restrict__ order,
                                               const int* __restrict__ small,
                                               const float* __restrict__ agg,
                                               const float* __restrict__ Wa,
                                               const float* __restrict__ ba,
                                               const float* __restrict__ ln_g,
                                               const float* __restrict__ ln_b,
                                               const float* __restrict__ skipw,
                                               float* __restrict__ out) {
    __shared__ float xs[4096];
    __shared__ float res_s[4096];
    int tid = threadIdx.x, wv = tid >> 6, lane = tid & 63;
    int wid = blockIdx.x;
    int cb1 = small[17], cb2 = small[18], cb3 = small[19], cb4 = small[20];
    if (wid >= cb4) return;
    int t = (wid >= cb1) + (wid >= cb2) + (wid >= cb3);
    int cbt = small[16 + t];
    int noff = small[8 + t], cntt = small[t];
    int pos = noff + (wid - cbt) * 64 + lane;
    int end = noff + cntt;
    bool valid = pos < end;
    int node = order[valid ? pos : end - 1];
    t = __builtin_amdgcn_readfirstlane(t);
    int wvu = __builtin_amdgcn_readfirstlane(wv);

    const float* ar = agg + node * 64 + wvu * 16;
    float4 a0 = *(const float4*)(ar + 0), a1 = *(const float4*)(ar + 4),
           a2 = *(const float4*)(ar + 8), a3 = *(const float4*)(ar + 12);
    float st[16] = { gelu_f(a0.x), gelu_f(a0.y), gelu_f(a0.z), gelu_f(a0.w),
                     gelu_f(a1.x), gelu_f(a1.y), gelu_f(a1.z), gelu_f(a1.w),
                     gelu_f(a2.x), gelu_f(a2.y), gelu_f(a2.z), gelu_f(a2.w),
                     gelu_f(a3.x), gelu_f(a3.y), gelu_f(a3.z), gelu_f(a3.w) };
#pragma unroll
    for (int k = 0; k < 16; ++k) xs[(wvu * 16 + k) * 64 + lane] = st[k];
    __syncthreads();

    float acc[16];
    const float* Bp = ba + t * 64 + wvu * 16;
#pragma unroll
    for (int c = 0; c < 16; c += 4) {
        float4 b4 = *(const float4*)(Bp + c);
        acc[c] = b4.x; acc[c + 1] = b4.y; acc[c + 2] = b4.z; acc[c + 3] = b4.w;
    }
    const float* Wp = Wa + t * 4096 + wvu * 16;
#pragma unroll 4
    for (int i = 0; i < 64; ++i) {
        float xi = xs[i * 64 + lane];
#pragma unroll
        for (int c = 0; c < 16; c += 4) {
            float4 w4 = *(const float4*)(Wp + i * 64 + c);
            acc[c]     = fmaf(xi, w4.x, acc[c]);
            acc[c + 1] = fmaf(xi, w4.y, acc[c + 1]);
            acc[c + 2] = fmaf(xi, w4.z, acc[c + 2]);
            acc[c + 3] = fmaf(xi, w4.w, acc[c + 3]);
        }
    }
    float sk = 1.0f / (1.0f + __expf(-skipw[t]));
    float om = 1.0f - sk;
    const float* xrow = x + node * 64 + wvu * 16;
#pragma unroll
    for (int c = 0; c < 16; c += 4) {
        float4 xv = *(const float4*)(xrow + c);
        acc[c]     = acc[c] * sk + xv.x * om;
        acc[c + 1] = acc[c + 1] * sk + xv.y * om;
        acc[c + 2] = acc[c + 2] * sk + xv.z * om;
        acc[c + 3] = acc[c + 3] * sk + xv.w * om;
    }
#pragma unroll
    for (int k = 0; k < 16; ++k) res_s[(wvu * 16 + k) * 64 + lane] = acc[k];
    __syncthreads();

    float sum = 0.0f, ssq = 0.0f;
#pragma unroll
    for (int c = 0; c < 64; ++c) {
        float rv = res_s[c * 64 + lane];
        sum += rv; ssq = fmaf(rv, rv, ssq);
    }
    float mu = sum * (1.0f / 64.0f);
    float var = ssq * (1.0f / 64.0f) - mu * mu;
    float rstd = rsqrtf(var + 1e-5f);
    const float* lg = ln_g + t * 64 + wvu * 16;
    const float* lb = ln_b + t * 64 + wvu * 16;
    if (valid) {
        float* op = out + node * 64 + wvu * 16;
#pragma unroll
        for (int c = 0; c < 16; c += 4) {
            float4 ov;
            ov.x = (acc[c]     - mu) * rstd * lg[c]     + lb[c];
            ov.y = (acc[c + 1] - mu) * rstd * lg[c + 1] + lb[c + 1];
            ov.z = (acc[c + 2] - mu) * rstd * lg[c + 2] + lb[c + 2];
            ov.w = (acc[c + 3] - mu) * rstd * lg[c + 3] + lb[c + 3];
            *(float4*)(op + c) = ov;
        }
    }
}

extern "C" void kernel_launch(void* const* d_in, const int* in_sizes, int n_in,
                              void* d_out, int out_size, void* d_ws, size_t ws_size,
                              hipStream_t stream) {
    const float* x       = (const float*)d_in[0];
    const int*   ntype   = (const int*)d_in[1];
    const int*   ei      = (const int*)d_in[2];
    const int*   et      = (const int*)d_in[3];
    const float* Wk      = (const float*)d_in[4];
    const float* bk      = (const float*)d_in[5];
    const float* Wq      = (const float*)d_in[6];
    const float* bq      = (const float*)d_in[7];
    const float* Wv      = (const float*)d_in[8];
    const float* bv      = (const float*)d_in[9];
    const float* Wa      = (const float*)d_in[10];
    const float* ba      = (const float*)d_in[11];
    const float* ln_g    = (const float*)d_in[12];
    const float* ln_b    = (const float*)d_in[13];
    const float* rel_pri = (const float*)d_in[14];
    const float* rel_att = (const float*)d_in[15];
    const float* rel_msg = (const float*)d_in[16];
    const float* skipw   = (const float*)d_in[17];
    float* out = (float*)d_out;

    float* ws = (float*)d_ws;
    unsigned* KVu = (unsigned*)(ws + OFF_KV);
    float* Qn  = ws + OFF_QN;
    float* agg = ws + OFF_AGG;
    int* rs    = (int*)(ws + OFF_RS);
    int* cnt   = (int*)(ws + OFF_CNT);
    int* part  = (int*)(ws + OFF_PART);
    int* small = (int*)(ws + OFF_SMALL);
    int* bth   = (int*)(ws + OFF_BTH);
    int* order = (int*)(ws + OFF_ORDER);
    int* col   = (int*)(ws + OFF_COL);

    hipMemsetAsync(cnt, 0, 800000 * sizeof(int), stream);
    hist_k<<<3125, 256, 0, stream>>>(ei, ntype, cnt, bth);
    tscan_k<<<1, 64, 0, stream>>>(bth, small);
    scan1_k<<<196, 256, 0, stream>>>(cnt, rs, part);
    scan2_k<<<1, 256, 0, stream>>>(part);
    scan3_k<<<196, 256, 0, stream>>>(rs, part, ntype, bth, order);
    scatter_col_k<<<3125, 256, 0, stream>>>(ei, et, rs, cnt, col);
    kqv_k<<<786, 256, 0, stream>>>(x, order, small, Wk, bk, Wq, bq, Wv, bv, Qn, KVu);
    attn_k<<<12500, 256, 0, stream>>>(Qn, KVu, rs, col, rel_att, rel_msg, rel_pri, agg);
    final_k<<<786, 256, 0, stream>>>(x, order, small, agg, Wa, ba, ln_g, ln_b, skipw, out);
}

// Round 7
// 260.909 us; speedup vs baseline: 3.2985x; 1.0055x over previous
//
#include <hip/hip_runtime.h>
#include <math.h>

#define N_NODES 50000
#define N_EDGES 800000

// workspace layout (float/u32-element offsets)
#define OFF_KV     0          // u32[N*64]: interleaved bf16 (K lo16, V hi16)
#define OFF_QN     3200000    // float[N*64]
#define OFF_AGG    6400000    // float[N*64]
#define OFF_RS     9600000    // int[50001]
#define OFF_CNT    9660000    // int[800000] (stride-16 padded degree counters)
#define OFF_PART   10460000   // int[256]
#define OFF_SMALL  10460300   // int[32]
#define OFF_BTH    10460400   // int[4*196]
#define OFF_ORDER  10461200   // int[50000]
#define OFF_COL    10520000   // int[800000]

__device__ __forceinline__ float gelu_f(float a) {
    return 0.5f * a * (1.0f + erff(a * 0.70710678118654752f));
}

__device__ __forceinline__ unsigned pack_kv(float kf, float vf) {
    unsigned ku = __float_as_uint(kf);
    ku = (ku + 0x7FFFu + ((ku >> 16) & 1u)) >> 16;
    unsigned vu = __float_as_uint(vf);
    vu = (vu + 0x7FFFu + ((vu >> 16) & 1u)) & 0xFFFF0000u;
    return vu | ku;
}

// edge-degree histogram (padded counters) + fused per-block node-type histogram
__global__ __launch_bounds__(256) void hist_k(const int* __restrict__ ei,
                                              const int* __restrict__ ntype,
                                              int* __restrict__ cnt,
                                              int* __restrict__ bth) {
    int e = blockIdx.x * 256 + threadIdx.x;      // exact 800000
    atomicAdd(&cnt[ei[N_EDGES + e] << 4], 1);
    if (blockIdx.x < 196) {
        __shared__ int wc[4][4];
        int tid = threadIdx.x, w = tid >> 6, lane = tid & 63;
        int i = blockIdx.x * 256 + tid;
        int t = (i < N_NODES) ? ntype[i] : 255;
#pragma unroll
        for (int tt = 0; tt < 4; ++tt) {
            unsigned long long m = __ballot(t == tt);
            if (lane == 0) wc[w][tt] = __popcll(m);
        }
        __syncthreads();
        if (tid < 4)
            bth[tid * 196 + blockIdx.x] = wc[0][tid] + wc[1][tid] + wc[2][tid] + wc[3][tid];
    }
}

__global__ __launch_bounds__(64) void tscan_k(int* __restrict__ bth,
                                              int* __restrict__ small) {
    __shared__ int tot[4];
    __shared__ int noff_s[4];
    int t = threadIdx.x;
    if (t < 4) {
        int s = 0;
        for (int b = 0; b < 196; ++b) s += bth[t * 196 + b];
        tot[t] = s;
    }
    __syncthreads();
    if (t == 0) {
        int o = 0, cb = 0;
        for (int k = 0; k < 4; ++k) {
            small[k] = tot[k];
            small[8 + k] = o; noff_s[k] = o;
            small[16 + k] = cb;
            o += tot[k]; cb += (tot[k] + 63) >> 6;
        }
        small[12] = o; small[20] = cb;
    }
    __syncthreads();
    if (t < 4) {
        int run = noff_s[t];
        for (int b = 0; b < 196; ++b) {
            int c = bth[t * 196 + b];
            bth[t * 196 + b] = run;
            run += c;
        }
    }
}

__global__ __launch_bounds__(256) void scan1_k(const int* __restrict__ cnt,
                                               int* __restrict__ rs,
                                               int* __restrict__ part) {
    int tid = threadIdx.x;
    int i = blockIdx.x * 256 + tid;
    int lane = tid & 63, w = tid >> 6;
    int c = (i < N_NODES) ? cnt[i << 4] : 0;
    int v = c;
#pragma unroll
    for (int o = 1; o < 64; o <<= 1) { int u = __shfl_up(v, o); if (lane >= o) v += u; }
    __shared__ int wsum[4];
    if (lane == 63) wsum[w] = v;
    __syncthreads();
    int base = 0;
#pragma unroll
    for (int k = 0; k < 4; ++k) if (k < w) base += wsum[k];
    if (i < N_NODES) rs[i] = base + v - c;
    if (tid == 255) part[blockIdx.x] = base + v;
}

__global__ __launch_bounds__(256) void scan2_k(int* __restrict__ part) {
    int tid = threadIdx.x;
    int lane = tid & 63, w = tid >> 6;
    int c = (tid < 196) ? part[tid] : 0;
    int v = c;
#pragma unroll
    for (int o = 1; o < 64; o <<= 1) { int u = __shfl_up(v, o); if (lane >= o) v += u; }
    __shared__ int wsum[4];
    if (lane == 63) wsum[w] = v;
    __syncthreads();
    int base = 0;
#pragma unroll
    for (int k = 0; k < 4; ++k) if (k < w) base += wsum[k];
    if (tid < 196) part[tid] = base + v - c;   // exclusive
}

// finalize rs + fused type-bucket scatter (ballot ranks, no atomics)
__global__ __launch_bounds__(256) void scan3_k(int* __restrict__ rs,
                                               const int* __restrict__ part,
                                               const int* __restrict__ ntype,
                                               const int* __restrict__ bth,
                                               int* __restrict__ order) {
    int tid = threadIdx.x, w = tid >> 6, lane = tid & 63;
    int i = blockIdx.x * 256 + tid;
    if (i < N_NODES) rs[i] += part[blockIdx.x];
    if (i == 0) rs[N_NODES] = N_EDGES;
    __shared__ int wc[4][4];
    int t = (i < N_NODES) ? ntype[i] : 255;
    int myrank = 0;
#pragma unroll
    for (int tt = 0; tt < 4; ++tt) {
        unsigned long long m = __ballot(t == tt);
        if (lane == 0) wc[w][tt] = __popcll(m);
        if (t == tt) myrank = __popcll(m & ((1ull << lane) - 1ull));
    }
    __syncthreads();
    if (t < 4) {
        int base = 0;
#pragma unroll
        for (int w2 = 0; w2 < 4; ++w2) if (w2 < w) base += wc[w2][t];
        order[bth[t * 196 + blockIdx.x] + base + myrank] = i;
    }
}

// CSR column scatter; consumes cnt by atomic decrement (in-row order reversed, harmless)
__global__ __launch_bounds__(256) void scatter_col_k(const int* __restrict__ ei,
                                                     const int* __restrict__ et,
                                                     const int* __restrict__ rs,
                                                     int* __restrict__ cnt,
                                                     int* __restrict__ col) {
    int e = blockIdx.x * 256 + threadIdx.x;      // exact 800000
    int tgt = ei[N_EDGES + e];
    int old = atomicSub(&cnt[tgt << 4], 1);
    col[rs[tgt] + old - 1] = ei[e] | (et[e] << 20);
}

// 64-node x 16-col slice of a typed linear into registers (wave-uniform weights)
__device__ __forceinline__ void mat16(const float* __restrict__ W,
                                      const float* __restrict__ B,
                                      const float* xs, int lane, int wvu,
                                      float acc[16]) {
    const float* Bp = B + wvu * 16;
#pragma unroll
    for (int c = 0; c < 16; c += 4) {
        float4 b4 = *(const float4*)(Bp + c);
        acc[c] = b4.x; acc[c + 1] = b4.y; acc[c + 2] = b4.z; acc[c + 3] = b4.w;
    }
    const float* Wp = W + wvu * 16;
#pragma unroll 4
    for (int i = 0; i < 64; ++i) {
        float xi = xs[i * 64 + lane];
#pragma unroll
        for (int c = 0; c < 16; c += 4) {
            float4 w4 = *(const float4*)(Wp + i * 64 + c);
            acc[c]     = fmaf(xi, w4.x, acc[c]);
            acc[c + 1] = fmaf(xi, w4.y, acc[c + 1]);
            acc[c + 2] = fmaf(xi, w4.z, acc[c + 2]);
            acc[c + 3] = fmaf(xi, w4.w, acc[c + 3]);
        }
    }
}

__global__ __launch_bounds__(256) void kqv_k(const float* __restrict__ x,
                                             const int* __restrict__ order,
                                             const int* __restrict__ small,
                                             const float* __restrict__ Wk, const float* __restrict__ bk,
                                             const float* __restrict__ Wq, const float* __restrict__ bq,
                                             const float* __restrict__ Wv, const float* __restrict__ bv,
                                             float* __restrict__ Qn,
                                             unsigned* __restrict__ KVu) {
    __shared__ float xs[4096];
    int tid = threadIdx.x, wv = tid >> 6, lane = tid & 63;
    int wid = blockIdx.x;
    int cb1 = small[17], cb2 = small[18], cb3 = small[19], cb4 = small[20];
    if (wid >= cb4) return;
    int t = (wid >= cb1) + (wid >= cb2) + (wid >= cb3);
    int cbt = small[16 + t];
    int noff = small[8 + t], cntt = small[t];
    int pos = noff + (wid - cbt) * 64 + lane;
    int end = noff + cntt;
    bool valid = pos < end;
    int node = order[valid ? pos : end - 1];
    t = __builtin_amdgcn_readfirstlane(t);
    int wvu = __builtin_amdgcn_readfirstlane(wv);

    const float* xr = x + node * 64 + wvu * 16;
    float4 a0 = *(const float4*)(xr + 0), a1 = *(const float4*)(xr + 4),
           a2 = *(const float4*)(xr + 8), a3 = *(const float4*)(xr + 12);
    float st[16] = { a0.x, a0.y, a0.z, a0.w, a1.x, a1.y, a1.z, a1.w,
                     a2.x, a2.y, a2.z, a2.w, a3.x, a3.y, a3.z, a3.w };
#pragma unroll
    for (int k = 0; k < 16; ++k) xs[(wvu * 16 + k) * 64 + lane] = st[k];
    __syncthreads();

    float aq[16];
    mat16(Wq + t * 4096, bq + t * 64, xs, lane, wvu, aq);
    if (valid) {
        float* Op = Qn + node * 64 + wvu * 16;
#pragma unroll
        for (int c = 0; c < 16; c += 4) {
            float4 o4 = { aq[c], aq[c + 1], aq[c + 2], aq[c + 3] };
            *(float4*)(Op + c) = o4;
        }
    }
    float ak[16], av[16];
    mat16(Wk + t * 4096, bk + t * 64, xs, lane, wvu, ak);
    mat16(Wv + t * 4096, bv + t * 64, xs, lane, wvu, av);
    if (valid) {
        unsigned pk[16];
#pragma unroll
        for (int c = 0; c < 16; ++c) pk[c] = pack_kv(ak[c], av[c]);
        uint4* dst = (uint4*)(KVu + node * 64 + wvu * 16);
#pragma unroll
        for (int c = 0; c < 4; ++c)
            dst[c] = *(uint4*)&pk[c * 4];
    }
}

#define BF_LO(u) __uint_as_float((u) << 16)
#define BF_HI(u) __uint_as_float((u) & 0xFFFF0000u)

struct KVB { int cc[4]; uint2 a[4]; uint2 b[4]; };

// issue all 4 tiles of batch BT back-to-back (8 loads in flight, in-order consume)
#define LOAD_BATCH(BUF, BT) do {                                           \
    _Pragma("unroll")                                                      \
    for (int tt_ = 0; tt_ < 4; ++tt_) {                                    \
        int tile_ = (BT) * 4 + tt_;                                        \
        if (tile_ < nit) {                                                 \
            int idx_ = tile_ * 4 + g; if (idx_ > deg - 1) idx_ = deg - 1;  \
            int cc_ = col[r0 + idx_];                                      \
            BUF.cc[tt_] = cc_;                                             \
            const unsigned* kvp_ = KVu + (unsigned)(cc_ & 0xFFFFF) * 64;   \
            BUF.a[tt_] = *(const uint2*)(kvp_ + 2 * l);                    \
            BUF.b[tt_] = *(const uint2*)(kvp_ + 32 + 2 * l);               \
        }                                                                  \
    }                                                                      \
} while (0)

#define COMPUTE(CC, AA, BB, T) do {                                        \
    int rr_ = (CC) >> 20;                                                  \
    const float* qq_ = qp_s + rr_ * 64 + 2 * l;                            \
    float2 qA_ = *(const float2*)qq_;                                      \
    float2 qB_ = *(const float2*)(qq_ + 32);                               \
    float kA0_ = BF_LO((AA).x), vA0_ = BF_HI((AA).x);                      \
    float kA1_ = BF_LO((AA).y), vA1_ = BF_HI((AA).y);                      \
    float kB0_ = BF_LO((BB).x), vB0_ = BF_HI((BB).x);                      \
    float kB1_ = BF_LO((BB).y), vB1_ = BF_HI((BB).y);                      \
    float sA_ = fmaf(kA1_, qA_.y, kA0_ * qA_.x);                           \
    float sB_ = fmaf(kB1_, qB_.y, kB0_ * qB_.x);                           \
    sA_ += __shfl_xor(sA_, 1); sB_ += __shfl_xor(sB_, 1);                  \
    sA_ += __shfl_xor(sA_, 2); sB_ += __shfl_xor(sB_, 2);                  \
    sA_ += __shfl_xor(sA_, 4); sB_ += __shfl_xor(sB_, 4);                  \
    bool act_ = ((T) * 4 + g) < deg;                                       \
    float pA_ = act_ ? __expf(sA_) : 0.0f;                                 \
    float pB_ = act_ ? __expf(sB_) : 0.0f;                                 \
    dnA += pA_; dnB += pB_;                                                \
    _Pragma("unroll")                                                      \
    for (int k_ = 0; k_ < 5; ++k_) {                                       \
        bool mk_ = (rr_ == k_);                                            \
        float pAk_ = mk_ ? pA_ : 0.0f, pBk_ = mk_ ? pB_ : 0.0f;            \
        OA[k_].x = fmaf(pAk_, vA0_, OA[k_].x);                             \
        OA[k_].y = fmaf(pAk_, vA1_, OA[k_].y);                             \
        OB[k_].x = fmaf(pBk_, vB0_, OB[k_].x);                             \
        OB[k_].y = fmaf(pBk_, vB1_, OB[k_].y);                             \
    }                                                                      \
} while (0)

#define COMPUTE_BATCH(BUF, BT) do {                                        \
    _Pragma("unroll")                                                      \
    for (int tt_c = 0; tt_c < 4; ++tt_c) {                                 \
        int tile_c = (BT) * 4 + tt_c;                                      \
        if (tile_c < nit)                                                  \
            COMPUTE(BUF.cc[tt_c], BUF.a[tt_c], BUF.b[tt_c], tile_c);       \
    }                                                                      \
} while (0)

// fused per-node attention+aggregation: pairwise lane layout, dwordx2 gathers,
// batch-of-16-edges double-buffered pipeline (straight-line issue, in-order consume)
__global__ __launch_bounds__(256) void attn_k(const float* __restrict__ Qn,
                                              const unsigned* __restrict__ KVu,
                                              const int* __restrict__ rs,
                                              const int* __restrict__ col,
                                              const float* __restrict__ rel_att,
                                              const float* __restrict__ rel_msg,
                                              const float* __restrict__ rel_pri,
                                              float* __restrict__ agg) {
    __shared__ float lds[2816];
    const int tid = threadIdx.x, wv = tid >> 6, lane = tid & 63;
    const int g = lane >> 4, l = lane & 15;
    const int node = blockIdx.x * 4 + wv;        // exact 12500*4 = 50000
    float* q_s  = lds + wv * 704;                // [64] (reused for den[4] later)
    float* qp_s = q_s + 64;                      // [5][64]: qp[r][h*16+d]
    float* o_s  = qp_s + 320;                    // [5][64]

    // issue the serial-chain loads first
    int r0 = rs[node], r1 = rs[node + 1];
    float qv = Qn[node * 64 + lane];
    int deg = r1 - r0;
    if (deg == 0) {
        agg[node * 64 + lane] = 0.0f;
        return;
    }
    int nit = (deg + 3) >> 2;
    int nb = (nit + 3) >> 2;

    float dnA = 0.0f, dnB = 0.0f;
    float2 OA[5], OB[5];
#pragma unroll
    for (int k = 0; k < 5; ++k) { OA[k] = {0.f, 0.f}; OB[k] = {0.f, 0.f}; }

    // issue first two batches of KV gathers before computing qp (latency overlap)
    KVB X0, X1;
    LOAD_BATCH(X0, 0);
    if (nb > 1) LOAD_BATCH(X1, 1);

    q_s[lane] = qv;
    __builtin_amdgcn_wave_barrier();
    const int gb = g * 16;
    float4 qf0 = *(const float4*)(q_s + gb + 0);
    float4 qf1 = *(const float4*)(q_s + gb + 4);
    float4 qf2 = *(const float4*)(q_s + gb + 8);
    float4 qf3 = *(const float4*)(q_s + gb + 12);
#pragma unroll
    for (int r = 0; r < 5; ++r) {
        const float* A = rel_att + ((r * 4 + g) * 16 + l) * 16;
        float4 b0 = *(const float4*)(A + 0), b1 = *(const float4*)(A + 4),
               b2 = *(const float4*)(A + 8), b3 = *(const float4*)(A + 12);
        float acc = b0.x * qf0.x;
        acc = fmaf(b0.y, qf0.y, acc); acc = fmaf(b0.z, qf0.z, acc); acc = fmaf(b0.w, qf0.w, acc);
        acc = fmaf(b1.x, qf1.x, acc); acc = fmaf(b1.y, qf1.y, acc);
        acc = fmaf(b1.z, qf1.z, acc); acc = fmaf(b1.w, qf1.w, acc);
        acc = fmaf(b2.x, qf2.x, acc); acc = fmaf(b2.y, qf2.y, acc);
        acc = fmaf(b2.z, qf2.z, acc); acc = fmaf(b2.w, qf2.w, acc);
        acc = fmaf(b3.x, qf3.x, acc); acc = fmaf(b3.y, qf3.y, acc);
        acc = fmaf(b3.z, qf3.z, acc); acc = fmaf(b3.w, qf3.w, acc);
        qp_s[r * 64 + gb + l] = acc * rel_pri[r * 4 + g] * 0.25f;
    }
    __builtin_amdgcn_wave_barrier();

    // batch-level double-buffered main loop (static buffer names, rule #20)
    int b = 0;
    for (;;) {
        COMPUTE_BATCH(X0, b);
        if (++b >= nb) break;
        if (b + 1 < nb) LOAD_BATCH(X0, b + 1);
        COMPUTE_BATCH(X1, b);
        if (++b >= nb) break;
        if (b + 1 < nb) LOAD_BATCH(X1, b + 1);
    }

    // cross-group (edge-slot) reduction
#pragma unroll
    for (int k = 0; k < 5; ++k) {
        OA[k].x += __shfl_xor(OA[k].x, 16); OA[k].x += __shfl_xor(OA[k].x, 32);
        OA[k].y += __shfl_xor(OA[k].y, 16); OA[k].y += __shfl_xor(OA[k].y, 32);
        OB[k].x += __shfl_xor(OB[k].x, 16); OB[k].x += __shfl_xor(OB[k].x, 32);
        OB[k].y += __shfl_xor(OB[k].y, 16); OB[k].y += __shfl_xor(OB[k].y, 32);
    }
    dnA += __shfl_xor(dnA, 16); dnA += __shfl_xor(dnA, 32);
    dnB += __shfl_xor(dnB, 16); dnB += __shfl_xor(dnB, 32);

    if (g == 0) {
#pragma unroll
        for (int k = 0; k < 5; ++k) {
            *(float2*)(o_s + k * 64 + 2 * l) = OA[k];
            *(float2*)(o_s + k * 64 + 32 + 2 * l) = OB[k];
        }
        if (l == 0) { q_s[0] = dnA; q_s[2] = dnB; }   // den0, den2
        if (l == 8) { q_s[1] = dnA; q_s[3] = dnB; }   // den1, den3
    }
    __builtin_amdgcn_wave_barrier();

    // agg[h=g][f=l] = (sum_r sum_d O_r[g][d] * M[r][g][d][l]) / den[g]
    float F = 0.0f;
#pragma unroll
    for (int k = 0; k < 5; ++k) {
        const float* ob = o_s + k * 64 + gb;
        float4 o0 = *(const float4*)(ob + 0), o1 = *(const float4*)(ob + 4),
               o2 = *(const float4*)(ob + 8), o3 = *(const float4*)(ob + 12);
        const float* M = rel_msg + ((k * 4 + g) * 16) * 16 + l;
        F = fmaf(o0.x, M[0],   F); F = fmaf(o0.y, M[16],  F);
        F = fmaf(o0.z, M[32],  F); F = fmaf(o0.w, M[48],  F);
        F = fmaf(o1.x, M[64],  F); F = fmaf(o1.y, M[80],  F);
        F = fmaf(o1.z, M[96],  F); F = fmaf(o1.w, M[112], F);
        F = fmaf(o2.x, M[128], F); F = fmaf(o2.y, M[144], F);
        F = fmaf(o2.z, M[160], F); F = fmaf(o2.w, M[176], F);
        F = fmaf(o3.x, M[192], F); F = fmaf(o3.y, M[208], F);
        F = fmaf(o3.z, M[224], F); F = fmaf(o3.w, M[240], F);
    }
    float dsel = q_s[g];
    float rd = (dsel > 0.0f) ? (1.0f / dsel) : 0.0f;
    agg[node * 64 + lane] = F * rd;
}

// gelu -> typed linear -> skip mix -> per-type LayerNorm (bucketed, node-per-lane)
__global__ __launch_bounds__(256) void final_k(const float* __restrict__ x,
                                               const int* __restrict__ order,
                                               const int* __restrict__ small,
                                               const float* __restrict__ agg,
                                               const float* __restrict__ Wa,
                                               const float* __restrict__ ba,
                                               const float* __restrict__ ln_g,
                                               const float* __restrict__ ln_b,
                                               const float* __restrict__ skipw,
                                               float* __restrict__ out) {
    __shared__ float xs[4096];
    __shared__ float res_s[4096];
    int tid = threadIdx.x, wv = tid >> 6, lane = tid & 63;
    int wid = blockIdx.x;
    int cb1 = small[17], cb2 = small[18], cb3 = small[19], cb4 = small[20];
    if (wid >= cb4) return;
    int t = (wid >= cb1) + (wid >= cb2) + (wid >= cb3);
    int cbt = small[16 + t];
    int noff = small[8 + t], cntt = small[t];
    int pos = noff + (wid - cbt) * 64 + lane;
    int end = noff + cntt;
    bool valid = pos < end;
    int node = order[valid ? pos : end - 1];
    t = __builtin_amdgcn_readfirstlane(t);
    int wvu = __builtin_amdgcn_readfirstlane(wv);

    const float* ar = agg + node * 64 + wvu * 16;
    float4 a0 = *(const float4*)(ar + 0), a1 = *(const float4*)(ar + 4),
           a2 = *(const float4*)(ar + 8), a3 = *(const float4*)(ar + 12);
    float st[16] = { gelu_f(a0.x), gelu_f(a0.y), gelu_f(a0.z), gelu_f(a0.w),
                     gelu_f(a1.x), gelu_f(a1.y), gelu_f(a1.z), gelu_f(a1.w),
                     gelu_f(a2.x), gelu_f(a2.y), gelu_f(a2.z), gelu_f(a2.w),
                     gelu_f(a3.x), gelu_f(a3.y), gelu_f(a3.z), gelu_f(a3.w) };
#pragma unroll
    for (int k = 0; k < 16; ++k) xs[(wvu * 16 + k) * 64 + lane] = st[k];
    __syncthreads();

    float acc[16];
    const float* Bp = ba + t * 64 + wvu * 16;
#pragma unroll
    for (int c = 0; c < 16; c += 4) {
        float4 b4 = *(const float4*)(Bp + c);
        acc[c] = b4.x; acc[c + 1] = b4.y; acc[c + 2] = b4.z; acc[c + 3] = b4.w;
    }
    const float* Wp = Wa + t * 4096 + wvu * 16;
#pragma unroll 4
    for (int i = 0; i < 64; ++i) {
        float xi = xs[i * 64 + lane];
#pragma unroll
        for (int c = 0; c < 16; c += 4) {
            float4 w4 = *(const float4*)(Wp + i * 64 + c);
            acc[c]     = fmaf(xi, w4.x, acc[c]);
            acc[c + 1] = fmaf(xi, w4.y, acc[c + 1]);
            acc[c + 2] = fmaf(xi, w4.z, acc[c + 2]);
            acc[c + 3] = fmaf(xi, w4.w, acc[c + 3]);
        }
    }
    float sk = 1.0f / (1.0f + __expf(-skipw[t]));
    float om = 1.0f - sk;
    const float* xrow = x + node * 64 + wvu * 16;
#pragma unroll
    for (int c = 0; c < 16; c += 4) {
        float4 xv = *(const float4*)(xrow + c);
        acc[c]     = acc[c] * sk + xv.x * om;
        acc[c + 1] = acc[c + 1] * sk + xv.y * om;
        acc[c + 2] = acc[c + 2] * sk + xv.z * om;
        acc[c + 3] = acc[c + 3] * sk + xv.w * om;
    }
#pragma unroll
    for (int k = 0; k < 16; ++k) res_s[(wvu * 16 + k) * 64 + lane] = acc[k];
    __syncthreads();

    float sum = 0.0f, ssq = 0.0f;
#pragma unroll
    for (int c = 0; c < 64; ++c) {
        float rv = res_s[c * 64 + lane];
        sum += rv; ssq = fmaf(rv, rv, ssq);
    }
    float mu = sum * (1.0f / 64.0f);
    float var = ssq * (1.0f / 64.0f) - mu * mu;
    float rstd = rsqrtf(var + 1e-5f);
    const float* lg = ln_g + t * 64 + wvu * 16;
    const float* lb = ln_b + t * 64 + wvu * 16;
    if (valid) {
        float* op = out + node * 64 + wvu * 16;
#pragma unroll
        for (int c = 0; c < 16; c += 4) {
            float4 ov;
            ov.x = (acc[c]     - mu) * rstd * lg[c]     + lb[c];
            ov.y = (acc[c + 1] - mu) * rstd * lg[c + 1] + lb[c + 1];
            ov.z = (acc[c + 2] - mu) * rstd * lg[c + 2] + lb[c + 2];
            ov.w = (acc[c + 3] - mu) * rstd * lg[c + 3] + lb[c + 3];
            *(float4*)(op + c) = ov;
        }
    }
}

extern "C" void kernel_launch(void* const* d_in, const int* in_sizes, int n_in,
                              void* d_out, int out_size, void* d_ws, size_t ws_size,
                              hipStream_t stream) {
    const float* x       = (const float*)d_in[0];
    const int*   ntype   = (const int*)d_in[1];
    const int*   ei      = (const int*)d_in[2];
    const int*   et      = (const int*)d_in[3];
    const float* Wk      = (const float*)d_in[4];
    const float* bk      = (const float*)d_in[5];
    const float* Wq      = (const float*)d_in[6];
    const float* bq      = (const float*)d_in[7];
    const float* Wv      = (const float*)d_in[8];
    const float* bv      = (const float*)d_in[9];
    const float* Wa      = (const float*)d_in[10];
    const float* ba      = (const float*)d_in[11];
    const float* ln_g    = (const float*)d_in[12];
    const float* ln_b    = (const float*)d_in[13];
    const float* rel_pri = (const float*)d_in[14];
    const float* rel_att = (const float*)d_in[15];
    const float* rel_msg = (const float*)d_in[16];
    const float* skipw   = (const float*)d_in[17];
    float* out = (float*)d_out;

    float* ws = (float*)d_ws;
    unsigned* KVu = (unsigned*)(ws + OFF_KV);
    float* Qn  = ws + OFF_QN;
    float* agg = ws + OFF_AGG;
    int* rs    = (int*)(ws + OFF_RS);
    int* cnt   = (int*)(ws + OFF_CNT);
    int* part  = (int*)(ws + OFF_PART);
    int* small = (int*)(ws + OFF_SMALL);
    int* bth   = (int*)(ws + OFF_BTH);
    int* order = (int*)(ws + OFF_ORDER);
    int* col   = (int*)(ws + OFF_COL);

    hipMemsetAsync(cnt, 0, 800000 * sizeof(int), stream);
    hist_k<<<3125, 256, 0, stream>>>(ei, ntype, cnt, bth);
    tscan_k<<<1, 64, 0, stream>>>(bth, small);
    scan1_k<<<196, 256, 0, stream>>>(cnt, rs, part);
    scan2_k<<<1, 256, 0, stream>>>(part);
    scan3_k<<<196, 256, 0, stream>>>(rs, part, ntype, bth, order);
    scatter_col_k<<<3125, 256, 0, stream>>>(ei, et, rs, cnt, col);
    kqv_k<<<786, 256, 0, stream>>>(x, order, small, Wk, bk, Wq, bq, Wv, bv, Qn, KVu);
    attn_k<<<12500, 256, 0, stream>>>(Qn, KVu, rs, col, rel_att, rel_msg, rel_pri, agg);
    final_k<<<786, 256, 0, stream>>>(x, order, small, agg, Wa, ba, ln_g, ln_b, skipw, out);
}